// Round 10
// baseline (3331.342 us; speedup 1.0000x reference)
//
#include <hip/hip_runtime.h>
#include <hip/hip_bf16.h>
#include <hip/hip_cooperative_groups.h>

namespace cg = cooperative_groups;

#define P_ 50000
#define NL_ 2000
#define NQ_ 6000
#define L_ 8
#define P2L_ 128
#define P2Q_ 64
#define D_ 32
#define ITERS_ 8
#define GRID_ 512
#define RA_ 1563  // remap chunks for path-indexed arrays (P_*8/256)
#define RC_ 1500  // remap chunks for p2q pairs (NQ_*P2Q_/256)

typedef __hip_bfloat16 bf16;
typedef unsigned short u16;
typedef unsigned int u32;

__device__ __forceinline__ float bfb2f(u16 u) {
    union { u32 i; float f; } c; c.i = ((u32)u) << 16; return c.f;
}
__device__ __forceinline__ u16 f2bfb(float f) {
    union { bf16 h; u16 u; } c; c.h = __float2bfloat16(f); return c.u;
}
__device__ __forceinline__ u32 pk2(float a, float b) {
    return (u32)f2bfb(a) | ((u32)f2bfb(b) << 16);
}

__device__ __forceinline__ float tanh_fast(float x) {
    return 1.f - 2.f / (__expf(2.f * x) + 1.f);
}
__device__ __forceinline__ float4 tanh4(float4 a) {
    return make_float4(tanh_fast(a.x), tanh_fast(a.y), tanh_fast(a.z), tanh_fast(a.w));
}

// butterfly-order replicated state: hr[4s+c] = h[4*(i^s)+c] for this lane's i.
__device__ __forceinline__ void hr_rebuild(float* hr, float4 own) {
    hr[0] = own.x; hr[1] = own.y; hr[2] = own.z; hr[3] = own.w;
#pragma unroll
    for (int c = 0; c < 4; c++)  hr[4 + c]  = __shfl_xor(hr[c], 1, 64);
#pragma unroll
    for (int c = 0; c < 8; c++)  hr[8 + c]  = __shfl_xor(hr[c], 2, 64);
#pragma unroll
    for (int c = 0; c < 16; c++) hr[16 + c] = __shfl_xor(hr[c], 4, 64);
}

// acc += full-h @ W[:,4i..4i+3]; W in LDS at base, offs[s] = (i^s)*128+4i
__device__ __forceinline__ float4 matvec32o(const float* hr, const float* base,
                                            const int* offs, float4 acc) {
#pragma unroll
    for (int s = 0; s < 8; s++) {
        const float* u0 = base + offs[s];
#pragma unroll
        for (int c = 0; c < 4; c++) {
            const float4 u = *(const float4*)(u0 + 32 * c);
            const float hk = hr[4 * s + c];
            acc.x += hk * u.x; acc.y += hk * u.y;
            acc.z += hk * u.z; acc.w += hk * u.w;
        }
    }
    return acc;
}

// Runtime dtype probe (see earlier rounds): error prob ~1e-24.
__device__ bool detect_f32(const void* p, int n) {
    const u16* u = (const u16*)p;
    int m = n < 64 ? n : 64;
    bool bad = false;
    for (int k = 0; k < m; k++) {
        float v = bfb2f(u[k]);
        float av = fabsf(v);
        bool sane = (v == v) && (av <= 1e6f) && (av == 0.0f || av >= 1e-8f);
        bad |= !sane;
    }
    return bad;
}

// ---------------- input canonicalization + counter zeroing -------------------

struct CvtArgs { const void* p[40]; };

__global__ __launch_bounds__(256) void k_convert(CvtArgs a, float* __restrict__ dst,
                                                 int* __restrict__ counters) {
    static constexpr int N[40] = {
        50000,50000,50000,50000,50000,50000,50000,50000,50000,50000,
        2000,6000,6000,
        544,32,1024,32, 160,32,1024,32, 160,32,1024,32,
        2048,1024,32, 1024,1024,32, 1024,1024,32,
        512,16,256,16,16,1};
    if (blockIdx.x == 0 && threadIdx.x < 16) counters[threadIdx.x] = 0;
    int b = blockIdx.x, t = 0, off = 0;
    for (;;) {
        int nb = (N[t] + 255) >> 8;
        if (b < nb) break;
        b -= nb; off += N[t]; ++t;
    }
    const void* src = a.p[t];
    const int n = N[t];
    const bool isf = detect_f32(src, n);
    const int i = b * 256 + threadIdx.x;
    if (i < n)
        dst[off + i] = isf ? ((const float*)src)[i] : bfb2f(((const u16*)src)[i]);
}

// ---------------- mega args --------------------------------------------------

struct MegaArgs {
    const float *traffic, *packets, *eq_lambda, *apl, *emf, *plo, *atoff, *aton,
                *ar_a, *sigma, *capacity, *queue_size, *weight;
    const int *length, *model, *policy, *priority;
    const int *q2p, *l2p, *p2l, *p2l_deg, *p2q, *p2q_deg, *q2l;
    const float *pe_w1, *pe_b1, *pe_w2, *pe_b2;
    const float *qe_w1, *qe_b1, *qe_w2, *qe_b2;
    const float *le_w1, *le_b1, *le_w2, *le_b2;
    const float *prW, *prU, *prB, *qrW, *qrU, *qrB, *lrW, *lrU, *lrB;
    const float *ro_w1, *ro_b1, *ro_w2, *ro_b2, *ro_w3, *ro_b3;
    const void* raw_traffic;
    float *sps, *queue_state, *link_state, *zq, *zl;
    u16* pss;
    int *perm, *inv, *lens, *q2ps, *l2ps, *p2qs, *hist, *cursor;
    void* out;
};

// LDS layout (floats): prU@0(1024) qrW@1024 qrU@2048 prWq@3072 qrB@4096 prB@4128
// lrW@4160 lrU@5184 prWl@6208 lrB@7232 ; readout overlay: wl@0(817) xs@1024(1664)
#define SM_PRU 0
#define SM_QRW 1024
#define SM_QRU 2048
#define SM_PWQ 3072
#define SM_QRB 4096
#define SM_PRB 4128
#define SM_LRW 4160
#define SM_LRU 5184
#define SM_PWL 6208
#define SM_LRB 7232

__global__ __launch_bounds__(256, 2) void k_mega(MegaArgs A)
{
    cg::grid_group grid = cg::this_grid();
    __shared__ float smem[7264];
    __shared__ int s_flag;
    int* ism = (int*)smem;
    const int tid = threadIdx.x;
    const int bid = blockIdx.x;
    const int grp = tid >> 3, i8 = tid & 7;
    const int w = tid >> 6, lane = tid & 63;

    int offs[8];
#pragma unroll
    for (int s = 0; s < 8; s++) offs[s] = (i8 ^ s) * 128 + 4 * i8;

    // ---------- Ph0a: histogram of lengths (LDS-aggregated) ----------
    for (int c = bid; c < 196; c += GRID_) {
        if (tid < 8) ism[tid] = 0;
        __syncthreads();
        int p = c * 256 + tid;
        if (p < P_) atomicAdd(&ism[A.length[p] - 1], 1);
        __syncthreads();
        if (tid < 8 && ism[tid] > 0) atomicAdd(&A.hist[tid], ism[tid]);
        __syncthreads();
    }
    grid.sync();

    // ---------- Ph0b: scatter (counting sort) ----------
    for (int c = bid; c < 196; c += GRID_) {
        int* cnt = ism; int* cbase = ism + 8;
        if (tid < 8) cnt[tid] = 0;
        __syncthreads();
        int p = c * 256 + tid;
        int b = 0, r = 0;
        if (p < P_) { b = A.length[p] - 1; r = atomicAdd(&cnt[b], 1); }
        __syncthreads();
        if (tid < 8) {
            int pre = 0;
#pragma unroll
            for (int k = 0; k < 8; k++) pre += (k < tid) ? A.hist[k] : 0;
            cbase[tid] = pre + (cnt[tid] > 0 ? atomicAdd(&A.cursor[tid], cnt[tid]) : 0);
        }
        __syncthreads();
        if (p < P_) { int pos = cbase[b] + r; A.perm[pos] = p; A.inv[p] = pos; }
        __syncthreads();
    }
    grid.sync();

    // ---------- Ph1: remap + embeddings (block-uniform branch per chunk) -----
    for (int c = bid; c < RA_ + RC_ + 196 + 24 + 500; c += GRID_) {
        if (c < RA_) {                                   // remap q2p/l2p/lens
            const int idx = c * 256 + tid;
            if (idx < P_ * 8) {
                const int j = idx >> 3, t = idx & 7;
                const int p = A.perm[j];
                A.q2ps[idx] = A.q2p[p * 8 + t];
                A.l2ps[idx] = A.l2p[p * 8 + t];
                if (t == 0) A.lens[j] = A.length[p];
            }
        } else if (c < RA_ + RC_) {                      // remap p2q -> sorted
            const int e = (c - RA_) * 256 + tid;
            if (e < NQ_ * P2Q_) {
                const int2 pr = ((const int2*)A.p2q)[e];
                ((int2*)A.p2qs)[e] = make_int2(A.inv[pr.x], pr.y);
            }
        } else if (c < RA_ + RC_ + 196) {                // path embed
            const int p = (c - RA_ - RC_) * 256 + tid;
            if (p < P_) {
                float f[10];
                f[0] = (A.traffic[p] - 1385.4059f) * (1.f / 859.8119f);
                f[1] = (A.packets[p] - 1.4015f)    * (1.f / 0.8933f);
                f[2] = (A.eq_lambda[p]- 1350.9712f)* (1.f / 858.3162f);
                f[3] = (A.apl[p]      - 0.9117f)   * (1.f / 0.9724f);
                f[4] = (A.emf[p]      - 6.6636f)   * (1.f / 4.7151f);
                f[5] = (A.plo[p]      - 0.9116f)   * (1.f / 1.6513f);
                f[6] = (A.atoff[p]    - 1.6649f)   * (1.f / 2.3564f);
                f[7] = (A.aton[p]     - 1.6649f)   * (1.f / 2.3564f);
                f[8] = A.ar_a[p];
                f[9] = A.sigma[p];
                const int mrow = 2 + A.model[p];
                float h1[32];
#pragma unroll
                for (int d = 0; d < 32; d++) {
                    float a = A.pe_b1[d] + A.pe_w1[mrow * 32 + d];
                    a += f[0] * A.pe_w1[0 * 32 + d];
                    a += f[1] * A.pe_w1[1 * 32 + d];
#pragma unroll
                    for (int j = 0; j < 8; j++) a += f[2 + j] * A.pe_w1[(9 + j) * 32 + d];
                    h1[d] = fmaxf(a, 0.f);
                }
                float* dst = A.sps + (size_t)A.inv[p] * 32;
#pragma unroll
                for (int d = 0; d < 32; d++) {
                    float a = A.pe_b2[d];
#pragma unroll
                    for (int k = 0; k < 32; k++) a += h1[k] * A.pe_w2[k * 32 + d];
                    dst[d] = fmaxf(a, 0.f);
                }
            }
        } else if (c < RA_ + RC_ + 196 + 24) {           // queue embed + zq
            const int q = (c - RA_ - RC_ - 196) * 256 + tid;
            if (q < NQ_) {
                float f0 = (A.queue_size[q] - 30259.1055f) * (1.f / 21410.0957f);
                float f4 = A.weight[q];
                int prow = 1 + A.priority[q];
                float h1[32];
#pragma unroll
                for (int d = 0; d < 32; d++) {
                    float a = A.qe_b1[d] + A.qe_w1[prow * 32 + d]
                            + f0 * A.qe_w1[0 * 32 + d] + f4 * A.qe_w1[4 * 32 + d];
                    h1[d] = fmaxf(a, 0.f);
                }
                float h2[32];
#pragma unroll
                for (int d = 0; d < 32; d++) {
                    float a = A.qe_b2[d];
#pragma unroll
                    for (int k = 0; k < 32; k++) a += h1[k] * A.qe_w2[k * 32 + d];
                    h2[d] = fmaxf(a, 0.f);
                    A.queue_state[q * 32 + d] = h2[d];
                }
#pragma unroll
                for (int d = 0; d < 32; d++) {
                    float a = A.prB[d];
#pragma unroll
                    for (int k = 0; k < 32; k++) a += h2[k] * A.prW[k * 32 + d];
                    A.zq[q * 32 + d] = a;
                }
            }
        } else {                                         // link embed + zl
            const int l = (c - RA_ - RC_ - 196 - 24) * 4 + w;
            const int deg = A.p2l_deg[l];
            float s = 0.f;
            if (lane < deg)      s += A.traffic[A.p2l[l * 256 + 2 * lane]];
            if (lane + 64 < deg) s += A.traffic[A.p2l[l * 256 + 2 * (lane + 64)]];
#pragma unroll
            for (int m = 1; m < 64; m <<= 1) s += __shfl_xor(s, m, 64);
            const float load = s / A.capacity[l];
            const int prow = 1 + A.policy[l];
            float* h1s = smem + w * 32;          // smem[0..255] scratch
            float* h2s = smem + 128 + w * 32;
            if (lane < 32) {
                float a = A.le_b1[lane] + A.le_w1[prow * 32 + lane]
                        + load * A.le_w1[lane];
                h1s[lane] = fmaxf(a, 0.f);
            }
            __syncthreads();
            if (lane < 32) {
                float a = A.le_b2[lane];
#pragma unroll
                for (int k = 0; k < 32; k++) a += h1s[k] * A.le_w2[k * 32 + lane];
                a = fmaxf(a, 0.f);
                A.link_state[l * 32 + lane] = a;
                h2s[lane] = a;
            }
            __syncthreads();
            if (lane < 32) {
                float a = 0.f;
#pragma unroll
                for (int k = 0; k < 32; k++) a += h2s[k] * A.prW[1024 + k * 32 + lane];
                A.zl[l * 32 + lane] = a;
            }
            __syncthreads();
        }
    }
    grid.sync();

    // ---------- Ph2: stage all loop weights in LDS once ----------
    for (int idx = tid; idx < 1024; idx += 256) {
        smem[SM_PRU + idx] = A.prU[idx];
        smem[SM_QRW + idx] = A.qrW[idx];
        smem[SM_QRU + idx] = A.qrU[idx];
        smem[SM_PWQ + idx] = A.prW[idx];
        smem[SM_LRW + idx] = A.lrW[idx];
        smem[SM_LRU + idx] = A.lrU[idx];
        smem[SM_PWL + idx] = A.prW[1024 + idx];
    }
    if (tid < 32) {
        smem[SM_QRB + tid] = A.qrB[tid];
        smem[SM_PRB + tid] = A.prB[tid];
        smem[SM_LRB + tid] = A.lrB[tid];
    }
    __syncthreads();

    // ---------- 8 message-passing iterations ----------
    for (int it = 0; it < ITERS_; ++it) {
        // --- A: path RNN (sorted, len-bounded) ---
        for (int c = bid; c < (P_ + 31) / 32; c += GRID_) {
            const int j = c * 32 + grp;
            if (j < P_) {
                const int len = A.lens[j];
                const int4 qi0 = *(const int4*)(A.q2ps + (size_t)j * 8);
                const int4 qi1 = *(const int4*)(A.q2ps + (size_t)j * 8 + 4);
                const int4 li0 = *(const int4*)(A.l2ps + (size_t)j * 8);
                const int4 li1 = *(const int4*)(A.l2ps + (size_t)j * 8 + 4);
                const int qidx[8] = {qi0.x, qi0.y, qi0.z, qi0.w, qi1.x, qi1.y, qi1.z, qi1.w};
                const int lidx[8] = {li0.x, li0.y, li0.z, li0.w, li1.x, li1.y, li1.z, li1.w};
                float4 own = *(const float4*)(A.sps + (size_t)j * 32 + 4 * i8);
                float hr[32];
                hr_rebuild(hr, own);
                float4 z;
                {
                    const float4 a = *(const float4*)(A.zq + (size_t)qidx[0] * 32 + 4 * i8);
                    const float4 b = *(const float4*)(A.zl + (size_t)lidx[0] * 32 + 4 * i8);
                    z = make_float4(a.x + b.x, a.y + b.y, a.z + b.z, a.w + b.w);
                }
#pragma unroll
                for (int t = 0; t < 8; t++) {
                    if (t >= len) break;
                    float4 acc = z;
                    if (t + 1 < len) {
                        const float4 a = *(const float4*)(A.zq + (size_t)qidx[t + 1] * 32 + 4 * i8);
                        const float4 b = *(const float4*)(A.zl + (size_t)lidx[t + 1] * 32 + 4 * i8);
                        z = make_float4(a.x + b.x, a.y + b.y, a.z + b.z, a.w + b.w);
                    }
                    acc = matvec32o(hr, smem + SM_PRU, offs, acc);
                    own = tanh4(acc);
                    uint2 w2;
                    w2.x = pk2(own.x, own.y);
                    w2.y = pk2(own.z, own.w);
                    *(uint2*)(A.pss + (size_t)j * 256 + t * 32 + 4 * i8) = w2;
                    if (t + 1 < len) hr_rebuild(hr, own);
                }
                *(float4*)(A.sps + (size_t)j * 32 + 4 * i8) = own;
            }
        }
        grid.sync();

        // --- B: queue update + zq (wave per queue) ---
        for (int c = bid; c < NQ_ / 4; c += GRID_) {
            const int q = c * 4 + w;
            const int g = lane >> 3;
            const int deg = A.p2q_deg[q];
            float4 ps = {0.f, 0.f, 0.f, 0.f};
            for (int j = g; j < deg; j += 8) {
                const int sj = A.p2qs[q * 128 + 2 * j];
                int pos = A.p2qs[q * 128 + 2 * j + 1] - 1;
                pos = pos < 0 ? 0 : (pos > 7 ? 7 : pos);
                const ushort4 v = *(const ushort4*)(A.pss + (size_t)sj * 256 + pos * 32 + 4 * i8);
                ps.x += bfb2f(v.x); ps.y += bfb2f(v.y);
                ps.z += bfb2f(v.z); ps.w += bfb2f(v.w);
            }
#pragma unroll
            for (int m = 8; m < 64; m <<= 1) {
                ps.x += __shfl_xor(ps.x, m, 64);
                ps.y += __shfl_xor(ps.y, m, 64);
                ps.z += __shfl_xor(ps.z, m, 64);
                ps.w += __shfl_xor(ps.w, m, 64);
            }
            const float4 qs = *(const float4*)(A.queue_state + (size_t)q * 32 + 4 * i8);
            float psr[32]; hr_rebuild(psr, ps);
            float qsr[32]; hr_rebuild(qsr, qs);
            float4 acc = *(const float4*)(smem + SM_QRB + 4 * i8);
            acc = matvec32o(psr, smem + SM_QRW, offs, acc);
            acc = matvec32o(qsr, smem + SM_QRU, offs, acc);
            const float4 nh = tanh4(acc);
            float nhr[32]; hr_rebuild(nhr, nh);
            float4 zacc = *(const float4*)(smem + SM_PRB + 4 * i8);
            zacc = matvec32o(nhr, smem + SM_PWQ, offs, zacc);
            if (g == 0) {
                *(float4*)(A.queue_state + (size_t)q * 32 + 4 * i8) = nh;
                *(float4*)(A.zq + (size_t)q * 32 + 4 * i8) = zacc;
            }
        }
        grid.sync();

        // --- C: link update + zl (wave per link) ---
        for (int c = bid; c < NL_ / 4; c += GRID_) {
            const int l = c * 4 + w;
            const int g = lane >> 3;
            float4 h = *(const float4*)(A.link_state + (size_t)l * 32 + 4 * i8);
            float hhr[32]; hr_rebuild(hhr, h);
#pragma unroll
            for (int t = 0; t < 3; t++) {
                const int qq = A.q2l[l * 3 + t];
                const float4 qg = *(const float4*)(A.queue_state + (size_t)qq * 32 + 4 * i8);
                float qgr[32]; hr_rebuild(qgr, qg);
                float4 acc = *(const float4*)(smem + SM_LRB + 4 * i8);
                acc = matvec32o(qgr, smem + SM_LRW, offs, acc);
                acc = matvec32o(hhr, smem + SM_LRU, offs, acc);
                h = tanh4(acc);
                hr_rebuild(hhr, h);
            }
            float4 zacc = make_float4(0.f, 0.f, 0.f, 0.f);
            zacc = matvec32o(hhr, smem + SM_PWL, offs, zacc);
            if (g == 0) {
                *(float4*)(A.link_state + (size_t)l * 32 + 4 * i8) = h;
                *(float4*)(A.zl + (size_t)l * 32 + 4 * i8) = zacc;
            }
        }
        grid.sync();
    }

    // ---------- readout ----------
    {
        float* wl = smem;            // 817 floats
        float* xs = smem + 1024;     // 32 groups x 52
        for (int idx = tid; idx < 512; idx += 256) wl[idx] = A.ro_w1[idx];
        if (tid < 256) wl[528 + tid] = A.ro_w2[tid];
        if (tid < 16) {
            wl[512 + tid] = A.ro_b1[tid];
            wl[784 + tid] = A.ro_b2[tid];
            wl[800 + tid] = A.ro_w3[tid];
        }
        if (tid == 0) {
            wl[816] = A.ro_b3[0];
            s_flag = detect_f32(A.raw_traffic, P_) ? 1 : 0;
        }
        __syncthreads();

        for (int c = bid; c < (P_ + 31) / 32; c += GRID_) {
            const int j = c * 32 + grp;
            if (j < P_) {
                const int len = A.lens[j];
                float qd = 0.f, ts = 0.f;
                float* x = xs + grp * 52;
                for (int t = 0; t < len; t++) {
                    const ushort4 hu = *(const ushort4*)(A.pss + (size_t)j * 256 + t * 32 + 4 * i8);
                    float4 hv;
                    hv.x = bfb2f(hu.x); hv.y = bfb2f(hu.y);
                    hv.z = bfb2f(hu.z); hv.w = bfb2f(hu.w);
                    *(float4*)&x[4 * i8] = hv;
                    float a0 = wl[512 + 2 * i8], a1 = wl[512 + 2 * i8 + 1];
#pragma unroll
                    for (int k = 0; k < 32; k += 4) {
                        const float4 xv = *(const float4*)&x[k];
                        const float2 u0 = *(const float2*)&wl[(k + 0) * 16 + 2 * i8];
                        const float2 u1 = *(const float2*)&wl[(k + 1) * 16 + 2 * i8];
                        const float2 u2 = *(const float2*)&wl[(k + 2) * 16 + 2 * i8];
                        const float2 u3 = *(const float2*)&wl[(k + 3) * 16 + 2 * i8];
                        a0 += xv.x * u0.x + xv.y * u1.x + xv.z * u2.x + xv.w * u3.x;
                        a1 += xv.x * u0.y + xv.y * u1.y + xv.z * u2.y + xv.w * u3.y;
                    }
                    a0 = fmaxf(a0, 0.f); a1 = fmaxf(a1, 0.f);
                    *(float2*)&x[32 + 2 * i8] = make_float2(a0, a1);
                    float c0 = wl[784 + 2 * i8], c1 = wl[784 + 2 * i8 + 1];
#pragma unroll
                    for (int k = 0; k < 16; k += 4) {
                        const float4 xv = *(const float4*)&x[32 + k];
                        const float2 u0 = *(const float2*)&wl[528 + (k + 0) * 16 + 2 * i8];
                        const float2 u1 = *(const float2*)&wl[528 + (k + 1) * 16 + 2 * i8];
                        const float2 u2 = *(const float2*)&wl[528 + (k + 2) * 16 + 2 * i8];
                        const float2 u3 = *(const float2*)&wl[528 + (k + 3) * 16 + 2 * i8];
                        c0 += xv.x * u0.x + xv.y * u1.x + xv.z * u2.x + xv.w * u3.x;
                        c1 += xv.x * u0.y + xv.y * u1.y + xv.z * u2.y + xv.w * u3.y;
                    }
                    c0 = fmaxf(c0, 0.f); c1 = fmaxf(c1, 0.f);
                    float pv = c0 * wl[800 + 2 * i8] + c1 * wl[800 + 2 * i8 + 1];
                    pv += __shfl_xor(pv, 1, 8);
                    pv += __shfl_xor(pv, 2, 8);
                    pv += __shfl_xor(pv, 4, 8);
                    const float occv = pv + wl[816];
                    const float inv = 1.f / A.capacity[A.l2ps[j * 8 + t]];
                    qd += occv * inv;
                    ts += inv;
                }
                if (i8 == 0) {
                    const int p = A.perm[j];
                    const float res = qd + (A.traffic[p] / A.packets[p]) * ts;
                    if (s_flag) ((float*)A.out)[p] = res;
                    else        ((bf16*)A.out)[p] = __float2bfloat16(res);
                }
            }
        }
    }
}

// ================= fallback kernels (round-9 proven path) ====================

__global__ __launch_bounds__(256) void k_hist(const int* __restrict__ length,
                                              int* __restrict__ hist) {
    __shared__ int hc[8];
    const int tid = threadIdx.x;
    if (tid < 8) hc[tid] = 0;
    __syncthreads();
    int p = blockIdx.x * 256 + tid;
    if (p < P_) atomicAdd(&hc[length[p] - 1], 1);
    __syncthreads();
    if (tid < 8 && hc[tid] > 0) atomicAdd(&hist[tid], hc[tid]);
}

__global__ __launch_bounds__(256) void k_scatter(const int* __restrict__ length,
                                                 const int* __restrict__ hist,
                                                 int* __restrict__ cursor,
                                                 int* __restrict__ perm,
                                                 int* __restrict__ inv) {
    __shared__ int cnt[8];
    __shared__ int base[8];
    const int tid = threadIdx.x;
    if (tid < 8) cnt[tid] = 0;
    __syncthreads();
    const int p = blockIdx.x * 256 + tid;
    int b = 0, r = 0;
    if (p < P_) { b = length[p] - 1; r = atomicAdd(&cnt[b], 1); }
    __syncthreads();
    if (tid < 8) {
        int pre = 0;
#pragma unroll
        for (int k = 0; k < 8; k++) pre += (k < tid) ? hist[k] : 0;
        base[tid] = pre + (cnt[tid] > 0 ? atomicAdd(&cursor[tid], cnt[tid]) : 0);
    }
    __syncthreads();
    if (p < P_) { const int pos = base[b] + r; perm[pos] = p; inv[p] = pos; }
}

__global__ __launch_bounds__(256) void k_fb(MegaArgs A, int phase, int it) {
    // phase 0: remap; 1: path embed; 2: queue embed; 3: link embed;
    // 4: rnn; 5: qupd; 6: lupd; 7: readout  (it unused except determinism)
    __shared__ float smem[7264];
    __shared__ int s_flag;
    const int tid = threadIdx.x;
    const int bid = blockIdx.x;
    const int grp = tid >> 3, i8 = tid & 7;
    const int w = tid >> 6, lane = tid & 63;
    int offs[8];
#pragma unroll
    for (int s = 0; s < 8; s++) offs[s] = (i8 ^ s) * 128 + 4 * i8;

    if (phase == 0) {
        if (bid < RA_) {
            const int idx = bid * 256 + tid;
            if (idx < P_ * 8) {
                const int j = idx >> 3, t = idx & 7;
                const int p = A.perm[j];
                A.q2ps[idx] = A.q2p[p * 8 + t];
                A.l2ps[idx] = A.l2p[p * 8 + t];
                if (t == 0) A.lens[j] = A.length[p];
            }
        } else {
            const int e = (bid - RA_) * 256 + tid;
            if (e < NQ_ * P2Q_) {
                const int2 pr = ((const int2*)A.p2q)[e];
                ((int2*)A.p2qs)[e] = make_int2(A.inv[pr.x], pr.y);
            }
        }
    } else if (phase == 1) {
        const int p = bid * 256 + tid;
        if (p < P_) {
            float f[10];
            f[0] = (A.traffic[p] - 1385.4059f) * (1.f / 859.8119f);
            f[1] = (A.packets[p] - 1.4015f)    * (1.f / 0.8933f);
            f[2] = (A.eq_lambda[p]- 1350.9712f)* (1.f / 858.3162f);
            f[3] = (A.apl[p]      - 0.9117f)   * (1.f / 0.9724f);
            f[4] = (A.emf[p]      - 6.6636f)   * (1.f / 4.7151f);
            f[5] = (A.plo[p]      - 0.9116f)   * (1.f / 1.6513f);
            f[6] = (A.atoff[p]    - 1.6649f)   * (1.f / 2.3564f);
            f[7] = (A.aton[p]     - 1.6649f)   * (1.f / 2.3564f);
            f[8] = A.ar_a[p];
            f[9] = A.sigma[p];
            const int mrow = 2 + A.model[p];
            float h1[32];
#pragma unroll
            for (int d = 0; d < 32; d++) {
                float a = A.pe_b1[d] + A.pe_w1[mrow * 32 + d];
                a += f[0] * A.pe_w1[0 * 32 + d];
                a += f[1] * A.pe_w1[1 * 32 + d];
#pragma unroll
                for (int j = 0; j < 8; j++) a += f[2 + j] * A.pe_w1[(9 + j) * 32 + d];
                h1[d] = fmaxf(a, 0.f);
            }
            float* dst = A.sps + (size_t)A.inv[p] * 32;
#pragma unroll
            for (int d = 0; d < 32; d++) {
                float a = A.pe_b2[d];
#pragma unroll
                for (int k = 0; k < 32; k++) a += h1[k] * A.pe_w2[k * 32 + d];
                dst[d] = fmaxf(a, 0.f);
            }
        }
    } else if (phase == 2) {
        const int q = bid * 256 + tid;
        if (q < NQ_) {
            float f0 = (A.queue_size[q] - 30259.1055f) * (1.f / 21410.0957f);
            float f4 = A.weight[q];
            int prow = 1 + A.priority[q];
            float h1[32];
#pragma unroll
            for (int d = 0; d < 32; d++) {
                float a = A.qe_b1[d] + A.qe_w1[prow * 32 + d]
                        + f0 * A.qe_w1[0 * 32 + d] + f4 * A.qe_w1[4 * 32 + d];
                h1[d] = fmaxf(a, 0.f);
            }
            float h2[32];
#pragma unroll
            for (int d = 0; d < 32; d++) {
                float a = A.qe_b2[d];
#pragma unroll
                for (int k = 0; k < 32; k++) a += h1[k] * A.qe_w2[k * 32 + d];
                h2[d] = fmaxf(a, 0.f);
                A.queue_state[q * 32 + d] = h2[d];
            }
#pragma unroll
            for (int d = 0; d < 32; d++) {
                float a = A.prB[d];
#pragma unroll
                for (int k = 0; k < 32; k++) a += h2[k] * A.prW[k * 32 + d];
                A.zq[q * 32 + d] = a;
            }
        }
    } else if (phase == 3) {
        const int l = bid * 4 + w;
        const int deg = A.p2l_deg[l];
        float s = 0.f;
        if (lane < deg)      s += A.traffic[A.p2l[l * 256 + 2 * lane]];
        if (lane + 64 < deg) s += A.traffic[A.p2l[l * 256 + 2 * (lane + 64)]];
#pragma unroll
        for (int m = 1; m < 64; m <<= 1) s += __shfl_xor(s, m, 64);
        const float load = s / A.capacity[l];
        const int prow = 1 + A.policy[l];
        float* h1s = smem + w * 32;
        float* h2s = smem + 128 + w * 32;
        if (lane < 32) {
            float a = A.le_b1[lane] + A.le_w1[prow * 32 + lane] + load * A.le_w1[lane];
            h1s[lane] = fmaxf(a, 0.f);
        }
        __syncthreads();
        if (lane < 32) {
            float a = A.le_b2[lane];
#pragma unroll
            for (int k = 0; k < 32; k++) a += h1s[k] * A.le_w2[k * 32 + lane];
            a = fmaxf(a, 0.f);
            A.link_state[l * 32 + lane] = a;
            h2s[lane] = a;
        }
        __syncthreads();
        if (lane < 32) {
            float a = 0.f;
#pragma unroll
            for (int k = 0; k < 32; k++) a += h2s[k] * A.prW[1024 + k * 32 + lane];
            A.zl[l * 32 + lane] = a;
        }
    } else if (phase == 4) {
        for (int idx = tid; idx < 1024; idx += 256) smem[idx] = A.prU[idx];
        __syncthreads();
        const int j = bid * 32 + grp;
        if (j >= P_) return;
        const int len = A.lens[j];
        const int4 qi0 = *(const int4*)(A.q2ps + (size_t)j * 8);
        const int4 qi1 = *(const int4*)(A.q2ps + (size_t)j * 8 + 4);
        const int4 li0 = *(const int4*)(A.l2ps + (size_t)j * 8);
        const int4 li1 = *(const int4*)(A.l2ps + (size_t)j * 8 + 4);
        const int qidx[8] = {qi0.x, qi0.y, qi0.z, qi0.w, qi1.x, qi1.y, qi1.z, qi1.w};
        const int lidx[8] = {li0.x, li0.y, li0.z, li0.w, li1.x, li1.y, li1.z, li1.w};
        float4 own = *(const float4*)(A.sps + (size_t)j * 32 + 4 * i8);
        float hr[32];
        hr_rebuild(hr, own);
        float4 z;
        {
            const float4 a = *(const float4*)(A.zq + (size_t)qidx[0] * 32 + 4 * i8);
            const float4 b = *(const float4*)(A.zl + (size_t)lidx[0] * 32 + 4 * i8);
            z = make_float4(a.x + b.x, a.y + b.y, a.z + b.z, a.w + b.w);
        }
#pragma unroll
        for (int t = 0; t < 8; t++) {
            if (t >= len) break;
            float4 acc = z;
            if (t + 1 < len) {
                const float4 a = *(const float4*)(A.zq + (size_t)qidx[t + 1] * 32 + 4 * i8);
                const float4 b = *(const float4*)(A.zl + (size_t)lidx[t + 1] * 32 + 4 * i8);
                z = make_float4(a.x + b.x, a.y + b.y, a.z + b.z, a.w + b.w);
            }
            acc = matvec32o(hr, smem, offs, acc);
            own = tanh4(acc);
            uint2 w2;
            w2.x = pk2(own.x, own.y);
            w2.y = pk2(own.z, own.w);
            *(uint2*)(A.pss + (size_t)j * 256 + t * 32 + 4 * i8) = w2;
            if (t + 1 < len) hr_rebuild(hr, own);
        }
        *(float4*)(A.sps + (size_t)j * 32 + 4 * i8) = own;
    } else if (phase == 5) {
#pragma unroll
        for (int jj = 0; jj < 4; jj++) {
            smem[tid + 256 * jj]        = A.qrW[tid + 256 * jj];
            smem[1024 + tid + 256 * jj] = A.qrU[tid + 256 * jj];
            smem[2048 + tid + 256 * jj] = A.prW[tid + 256 * jj];
        }
        if (tid < 32) { smem[3072 + tid] = A.qrB[tid]; smem[3104 + tid] = A.prB[tid]; }
        __syncthreads();
        const int g = lane >> 3;
        const int q = bid * 4 + w;
        const int deg = A.p2q_deg[q];
        float4 ps = {0.f, 0.f, 0.f, 0.f};
        for (int j = g; j < deg; j += 8) {
            const int sj = A.p2qs[q * 128 + 2 * j];
            int pos = A.p2qs[q * 128 + 2 * j + 1] - 1;
            pos = pos < 0 ? 0 : (pos > 7 ? 7 : pos);
            const ushort4 v = *(const ushort4*)(A.pss + (size_t)sj * 256 + pos * 32 + 4 * i8);
            ps.x += bfb2f(v.x); ps.y += bfb2f(v.y);
            ps.z += bfb2f(v.z); ps.w += bfb2f(v.w);
        }
#pragma unroll
        for (int m = 8; m < 64; m <<= 1) {
            ps.x += __shfl_xor(ps.x, m, 64);
            ps.y += __shfl_xor(ps.y, m, 64);
            ps.z += __shfl_xor(ps.z, m, 64);
            ps.w += __shfl_xor(ps.w, m, 64);
        }
        const float4 qs = *(const float4*)(A.queue_state + (size_t)q * 32 + 4 * i8);
        float psr[32]; hr_rebuild(psr, ps);
        float qsr[32]; hr_rebuild(qsr, qs);
        float4 acc = *(const float4*)(smem + 3072 + 4 * i8);
        acc = matvec32o(psr, smem, offs, acc);
        acc = matvec32o(qsr, smem + 1024, offs, acc);
        const float4 nh = tanh4(acc);
        float nhr[32]; hr_rebuild(nhr, nh);
        float4 zacc = *(const float4*)(smem + 3104 + 4 * i8);
        zacc = matvec32o(nhr, smem + 2048, offs, zacc);
        if (g == 0) {
            *(float4*)(A.queue_state + (size_t)q * 32 + 4 * i8) = nh;
            *(float4*)(A.zq + (size_t)q * 32 + 4 * i8) = zacc;
        }
    } else if (phase == 6) {
#pragma unroll
        for (int jj = 0; jj < 4; jj++) {
            smem[tid + 256 * jj]        = A.lrW[tid + 256 * jj];
            smem[1024 + tid + 256 * jj] = A.lrU[tid + 256 * jj];
            smem[2048 + tid + 256 * jj] = A.prW[1024 + tid + 256 * jj];
        }
        if (tid < 32) smem[3072 + tid] = A.lrB[tid];
        __syncthreads();
        const int g = lane >> 3;
        const int l = bid * 4 + w;
        float4 h = *(const float4*)(A.link_state + (size_t)l * 32 + 4 * i8);
        float hhr[32]; hr_rebuild(hhr, h);
#pragma unroll
        for (int t = 0; t < 3; t++) {
            const int qq = A.q2l[l * 3 + t];
            const float4 qg = *(const float4*)(A.queue_state + (size_t)qq * 32 + 4 * i8);
            float qgr[32]; hr_rebuild(qgr, qg);
            float4 acc = *(const float4*)(smem + 3072 + 4 * i8);
            acc = matvec32o(qgr, smem, offs, acc);
            acc = matvec32o(hhr, smem + 1024, offs, acc);
            h = tanh4(acc);
            hr_rebuild(hhr, h);
        }
        float4 zacc = make_float4(0.f, 0.f, 0.f, 0.f);
        zacc = matvec32o(hhr, smem + 2048, offs, zacc);
        if (g == 0) {
            *(float4*)(A.link_state + (size_t)l * 32 + 4 * i8) = h;
            *(float4*)(A.zl + (size_t)l * 32 + 4 * i8) = zacc;
        }
    } else {   // phase 7: readout
        float* wl = smem;
        float* xs = smem + 1024;
        for (int idx = tid; idx < 512; idx += 256) wl[idx] = A.ro_w1[idx];
        if (tid < 256) wl[528 + tid] = A.ro_w2[tid];
        if (tid < 16) {
            wl[512 + tid] = A.ro_b1[tid];
            wl[784 + tid] = A.ro_b2[tid];
            wl[800 + tid] = A.ro_w3[tid];
        }
        if (tid == 0) {
            wl[816] = A.ro_b3[0];
            s_flag = detect_f32(A.raw_traffic, P_) ? 1 : 0;
        }
        __syncthreads();
        const int j = bid * 32 + grp;
        if (j >= P_) return;
        const int len = A.lens[j];
        float qd = 0.f, ts = 0.f;
        float* x = xs + grp * 52;
        for (int t = 0; t < len; t++) {
            const ushort4 hu = *(const ushort4*)(A.pss + (size_t)j * 256 + t * 32 + 4 * i8);
            float4 hv;
            hv.x = bfb2f(hu.x); hv.y = bfb2f(hu.y); hv.z = bfb2f(hu.z); hv.w = bfb2f(hu.w);
            *(float4*)&x[4 * i8] = hv;
            float a0 = wl[512 + 2 * i8], a1 = wl[512 + 2 * i8 + 1];
#pragma unroll
            for (int k = 0; k < 32; k += 4) {
                const float4 xv = *(const float4*)&x[k];
                const float2 u0 = *(const float2*)&wl[(k + 0) * 16 + 2 * i8];
                const float2 u1 = *(const float2*)&wl[(k + 1) * 16 + 2 * i8];
                const float2 u2 = *(const float2*)&wl[(k + 2) * 16 + 2 * i8];
                const float2 u3 = *(const float2*)&wl[(k + 3) * 16 + 2 * i8];
                a0 += xv.x * u0.x + xv.y * u1.x + xv.z * u2.x + xv.w * u3.x;
                a1 += xv.x * u0.y + xv.y * u1.y + xv.z * u2.y + xv.w * u3.y;
            }
            a0 = fmaxf(a0, 0.f); a1 = fmaxf(a1, 0.f);
            *(float2*)&x[32 + 2 * i8] = make_float2(a0, a1);
            float c0 = wl[784 + 2 * i8], c1 = wl[784 + 2 * i8 + 1];
#pragma unroll
            for (int k = 0; k < 16; k += 4) {
                const float4 xv = *(const float4*)&x[32 + k];
                const float2 u0 = *(const float2*)&wl[528 + (k + 0) * 16 + 2 * i8];
                const float2 u1 = *(const float2*)&wl[528 + (k + 1) * 16 + 2 * i8];
                const float2 u2 = *(const float2*)&wl[528 + (k + 2) * 16 + 2 * i8];
                const float2 u3 = *(const float2*)&wl[528 + (k + 3) * 16 + 2 * i8];
                c0 += xv.x * u0.x + xv.y * u1.x + xv.z * u2.x + xv.w * u3.x;
                c1 += xv.x * u0.y + xv.y * u1.y + xv.z * u2.y + xv.w * u3.y;
            }
            c0 = fmaxf(c0, 0.f); c1 = fmaxf(c1, 0.f);
            float pv = c0 * wl[800 + 2 * i8] + c1 * wl[800 + 2 * i8 + 1];
            pv += __shfl_xor(pv, 1, 8);
            pv += __shfl_xor(pv, 2, 8);
            pv += __shfl_xor(pv, 4, 8);
            const float occv = pv + wl[816];
            const float inv = 1.f / A.capacity[A.l2ps[j * 8 + t]];
            qd += occv * inv;
            ts += inv;
        }
        if (i8 == 0) {
            const int p = A.perm[j];
            const float res = qd + (A.traffic[p] / A.packets[p]) * ts;
            if (s_flag) ((float*)A.out)[p] = res;
            else        ((bf16*)A.out)[p] = __float2bfloat16(res);
        }
    }
}

// ---------------- launcher ---------------------------------------------------

extern "C" void kernel_launch(void* const* d_in, const int* in_sizes, int n_in,
                              void* d_out, int out_size, void* d_ws, size_t ws_size,
                              hipStream_t stream)
{
    static const int CVT_N[40] = {
        50000,50000,50000,50000,50000,50000,50000,50000,50000,50000,
        2000,6000,6000,
        544,32,1024,32, 160,32,1024,32, 160,32,1024,32,
        2048,1024,32, 1024,1024,32, 1024,1024,32,
        512,16,256,16,16,1};

    CvtArgs ca;
    for (int i = 0; i < 13; i++) ca.p[i] = d_in[i];
    for (int i = 0; i < 27; i++) ca.p[13 + i] = d_in[24 + i];

    int off[41]; off[0] = 0;
    for (int i = 0; i < 40; i++) off[i + 1] = off[i] + CVT_N[i];
    int nblk = 0;
    for (int i = 0; i < 40; i++) nblk += (CVT_N[i] + 255) / 256;

    float* ws = (float*)d_ws;
    size_t base = ((size_t)off[40] + 63) & ~(size_t)63;
    float* sps         = ws + base;
    float* queue_state = sps + (size_t)P_ * 32;
    float* link_state  = queue_state + (size_t)NQ_ * 32;
    float* zq          = link_state + (size_t)NL_ * 32;
    float* zl          = zq + (size_t)NQ_ * 32;
    u16*   pss         = (u16*)(zl + (size_t)NL_ * 32);
    int*   perm        = (int*)(pss + (size_t)P_ * 256);
    int*   inv         = perm + P_;
    int*   lens        = inv + P_;
    int*   q2ps        = lens + P_;
    int*   l2ps        = q2ps + (size_t)P_ * 8;
    int*   p2qs        = l2ps + (size_t)P_ * 8;
    int*   counters    = p2qs + (size_t)NQ_ * 2 * P2Q_;

    MegaArgs A;
    A.traffic    = ws + off[0];  A.packets    = ws + off[1];
    A.eq_lambda  = ws + off[2];  A.apl        = ws + off[3];
    A.emf        = ws + off[4];  A.plo        = ws + off[5];
    A.atoff      = ws + off[6];  A.aton       = ws + off[7];
    A.ar_a       = ws + off[8];  A.sigma      = ws + off[9];
    A.capacity   = ws + off[10]; A.queue_size = ws + off[11];
    A.weight     = ws + off[12];
    A.length = (const int*)d_in[13]; A.model    = (const int*)d_in[14];
    A.policy = (const int*)d_in[15]; A.priority = (const int*)d_in[16];
    A.q2p = (const int*)d_in[17]; A.l2p = (const int*)d_in[18];
    A.p2l = (const int*)d_in[19]; A.p2l_deg = (const int*)d_in[20];
    A.p2q = (const int*)d_in[21]; A.p2q_deg = (const int*)d_in[22];
    A.q2l = (const int*)d_in[23];
    A.pe_w1 = ws + off[13]; A.pe_b1 = ws + off[14];
    A.pe_w2 = ws + off[15]; A.pe_b2 = ws + off[16];
    A.le_w1 = ws + off[17]; A.le_b1 = ws + off[18];
    A.le_w2 = ws + off[19]; A.le_b2 = ws + off[20];
    A.qe_w1 = ws + off[21]; A.qe_b1 = ws + off[22];
    A.qe_w2 = ws + off[23]; A.qe_b2 = ws + off[24];
    A.prW = ws + off[25]; A.prU = ws + off[26]; A.prB = ws + off[27];
    A.qrW = ws + off[28]; A.qrU = ws + off[29]; A.qrB = ws + off[30];
    A.lrW = ws + off[31]; A.lrU = ws + off[32]; A.lrB = ws + off[33];
    A.ro_w1 = ws + off[34]; A.ro_b1 = ws + off[35];
    A.ro_w2 = ws + off[36]; A.ro_b2 = ws + off[37];
    A.ro_w3 = ws + off[38]; A.ro_b3 = ws + off[39];
    A.raw_traffic = d_in[0];
    A.sps = sps; A.queue_state = queue_state; A.link_state = link_state;
    A.zq = zq; A.zl = zl; A.pss = pss;
    A.perm = perm; A.inv = inv; A.lens = lens;
    A.q2ps = q2ps; A.l2ps = l2ps; A.p2qs = p2qs;
    A.hist = counters; A.cursor = counters + 8;
    A.out = d_out;

    k_convert<<<nblk, 256, 0, stream>>>(ca, ws, counters);

    void* kargs[] = {(void*)&A};
    hipError_t e = hipLaunchCooperativeKernel((void*)k_mega, dim3(GRID_), dim3(256),
                                              kargs, 0, stream);
    if (e != hipSuccess) {
        // fallback: round-9 proven multi-launch sequence
        k_hist<<<(P_ + 255) / 256, 256, 0, stream>>>(A.length, A.hist);
        k_scatter<<<(P_ + 255) / 256, 256, 0, stream>>>(A.length, A.hist, A.cursor,
                                                        A.perm, A.inv);
        k_fb<<<RA_ + RC_, 256, 0, stream>>>(A, 0, 0);
        k_fb<<<(P_ + 255) / 256, 256, 0, stream>>>(A, 1, 0);
        k_fb<<<(NQ_ + 255) / 256, 256, 0, stream>>>(A, 2, 0);
        k_fb<<<NL_ / 4, 256, 0, stream>>>(A, 3, 0);
        for (int it = 0; it < ITERS_; ++it) {
            k_fb<<<(P_ + 31) / 32, 256, 0, stream>>>(A, 4, it);
            k_fb<<<NQ_ / 4, 256, 0, stream>>>(A, 5, it);
            k_fb<<<NL_ / 4, 256, 0, stream>>>(A, 6, it);
        }
        k_fb<<<(P_ + 31) / 32, 256, 0, stream>>>(A, 7, 0);
    }
}

// Round 11
// 669.769 us; speedup vs baseline: 4.9739x; 4.9739x over previous
//
#include <hip/hip_runtime.h>
#include <hip/hip_bf16.h>

#define P_ 50000
#define NL_ 2000
#define NQ_ 6000
#define L_ 8
#define P2L_ 128
#define P2Q_ 64
#define D_ 32
#define ITERS_ 8
#define RA_ 1563  // remap blocks for path-indexed arrays (P_*8/256)
#define RC_ 1500  // remap blocks for p2q pairs (NQ_*P2Q_/256)

typedef __hip_bfloat16 bf16;
typedef unsigned short u16;
typedef unsigned int u32;

__device__ __forceinline__ float bfb2f(u16 u) {
    union { u32 i; float f; } c; c.i = ((u32)u) << 16; return c.f;
}
__device__ __forceinline__ u16 f2bfb(float f) {
    union { bf16 h; u16 u; } c; c.h = __float2bfloat16(f); return c.u;
}
__device__ __forceinline__ u32 pk2(float a, float b) {
    return (u32)f2bfb(a) | ((u32)f2bfb(b) << 16);
}

__device__ __forceinline__ float tanh_fast(float x) {
    return 1.f - 2.f / (__expf(2.f * x) + 1.f);
}
__device__ __forceinline__ float4 tanh4(float4 a) {
    return make_float4(tanh_fast(a.x), tanh_fast(a.y), tanh_fast(a.z), tanh_fast(a.w));
}

// butterfly-order replicated state: hr[4s+c] = h[4*(i^s)+c] for this lane's i.
__device__ __forceinline__ void hr_rebuild(float* hr, float4 own) {
    hr[0] = own.x; hr[1] = own.y; hr[2] = own.z; hr[3] = own.w;
#pragma unroll
    for (int c = 0; c < 4; c++)  hr[4 + c]  = __shfl_xor(hr[c], 1, 64);
#pragma unroll
    for (int c = 0; c < 8; c++)  hr[8 + c]  = __shfl_xor(hr[c], 2, 64);
#pragma unroll
    for (int c = 0; c < 16; c++) hr[16 + c] = __shfl_xor(hr[c], 4, 64);
}

// acc += full-h @ W[:,4i..4i+3]; W in LDS at base, offs[s] = (i^s)*128+4i
__device__ __forceinline__ float4 matvec32o(const float* hr, const float* base,
                                            const int* offs, float4 acc) {
#pragma unroll
    for (int s = 0; s < 8; s++) {
        const float* u0 = base + offs[s];
#pragma unroll
        for (int c = 0; c < 4; c++) {
            const float4 u = *(const float4*)(u0 + 32 * c);
            const float hk = hr[4 * s + c];
            acc.x += hk * u.x; acc.y += hk * u.y;
            acc.z += hk * u.z; acc.w += hk * u.w;
        }
    }
    return acc;
}

// Runtime dtype probe (see earlier rounds): error prob ~1e-24.
__device__ bool detect_f32(const void* p, int n) {
    const u16* u = (const u16*)p;
    int m = n < 64 ? n : 64;
    bool bad = false;
    for (int k = 0; k < m; k++) {
        float v = bfb2f(u[k]);
        float av = fabsf(v);
        bool sane = (v == v) && (av <= 1e6f) && (av == 0.0f || av >= 1e-8f);
        bad |= !sane;
    }
    return bad;
}

// ---------------- input canonicalization + counter zeroing + dtype flag ------

struct CvtArgs { const void* p[40]; };

__global__ __launch_bounds__(256) void k_convert(CvtArgs a, float* __restrict__ dst,
                                                 int* __restrict__ counters) {
    static constexpr int N[40] = {
        50000,50000,50000,50000,50000,50000,50000,50000,50000,50000,
        2000,6000,6000,
        544,32,1024,32, 160,32,1024,32, 160,32,1024,32,
        2048,1024,32, 1024,1024,32, 1024,1024,32,
        512,16,256,16,16,1};
    if (blockIdx.x == 0 && threadIdx.x < 16) counters[threadIdx.x] = 0;
    int b = blockIdx.x, t = 0, off = 0;
    for (;;) {
        int nb = (N[t] + 255) >> 8;
        if (b < nb) break;
        b -= nb; off += N[t]; ++t;
    }
    const void* src = a.p[t];
    const int n = N[t];
    const bool isf = detect_f32(src, n);
    if (t == 0 && b == 0 && threadIdx.x == 0) counters[16] = isf ? 1 : 0;
    const int i = b * 256 + threadIdx.x;
    if (i < n)
        dst[off + i] = isf ? ((const float*)src)[i] : bfb2f(((const u16*)src)[i]);
}

// ---------------- counting sort by length: LDS-aggregated atomics ------------

__global__ __launch_bounds__(256) void k_hist(const int* __restrict__ length,
                                              int* __restrict__ hist) {
    __shared__ int hc[8];
    const int tid = threadIdx.x;
    if (tid < 8) hc[tid] = 0;
    __syncthreads();
    int p = blockIdx.x * 256 + tid;
    if (p < P_) atomicAdd(&hc[length[p] - 1], 1);
    __syncthreads();
    if (tid < 8 && hc[tid] > 0) atomicAdd(&hist[tid], hc[tid]);
}

__global__ __launch_bounds__(256) void k_scatter(const int* __restrict__ length,
                                                 const int* __restrict__ hist,
                                                 int* __restrict__ cursor,
                                                 int* __restrict__ perm,
                                                 int* __restrict__ inv) {
    __shared__ int cnt[8];
    __shared__ int base[8];
    const int tid = threadIdx.x;
    if (tid < 8) cnt[tid] = 0;
    __syncthreads();
    const int p = blockIdx.x * 256 + tid;
    int b = 0, r = 0;
    if (p < P_) { b = length[p] - 1; r = atomicAdd(&cnt[b], 1); }
    __syncthreads();
    if (tid < 8) {
        int pre = 0;
#pragma unroll
        for (int k = 0; k < 8; k++) pre += (k < tid) ? hist[k] : 0;
        base[tid] = pre + (cnt[tid] > 0 ? atomicAdd(&cursor[tid], cnt[tid]) : 0);
    }
    __syncthreads();
    if (p < P_) { const int pos = base[b] + r; perm[pos] = p; inv[p] = pos; }
}

// ---------------- remap into sorted index space ------------------------------

__global__ __launch_bounds__(256) void k_remap(
    const int* __restrict__ perm, const int* __restrict__ inv,
    const int* __restrict__ q2p, const int* __restrict__ l2p,
    const int* __restrict__ length, const int* __restrict__ p2q,
    int* __restrict__ q2ps, int* __restrict__ l2ps, int* __restrict__ lens,
    int* __restrict__ p2qs)
{
    const int blk = blockIdx.x;
    if (blk < RA_) {
        const int idx = blk * 256 + threadIdx.x;
        if (idx >= P_ * 8) return;
        const int j = idx >> 3, t = idx & 7;
        const int p = perm[j];
        q2ps[idx] = q2p[p * 8 + t];
        l2ps[idx] = l2p[p * 8 + t];
        if (t == 0) lens[j] = length[p];
    } else {
        const int e = (blk - RA_) * 256 + threadIdx.x;
        if (e >= NQ_ * P2Q_) return;
        const int2 pr = ((const int2*)p2q)[e];
        ((int2*)p2qs)[e] = make_int2(inv[pr.x], pr.y);
    }
}

// ---------------- path embed: thread/path, LDS-staged weights ----------------

__global__ __launch_bounds__(256) void k_path_embed(
    const float* __restrict__ traffic, const float* __restrict__ packets,
    const float* __restrict__ eq_lambda, const float* __restrict__ avg_pkts_lambda,
    const float* __restrict__ exp_max_factor, const float* __restrict__ pkts_lambda_on,
    const float* __restrict__ avg_t_off, const float* __restrict__ avg_t_on,
    const float* __restrict__ ar_a, const float* __restrict__ sigma,
    const int* __restrict__ model, const int* __restrict__ inv,
    const float* __restrict__ w1, const float* __restrict__ b1,
    const float* __restrict__ w2, const float* __restrict__ b2,
    float* __restrict__ sps)
{
    __shared__ float s_w1[544], s_w2[1024], s_b1[32], s_b2[32];
    const int tid = threadIdx.x;
    for (int idx = tid; idx < 544; idx += 256)  s_w1[idx] = w1[idx];
    for (int idx = tid; idx < 1024; idx += 256) s_w2[idx] = w2[idx];
    if (tid < 32) { s_b1[tid] = b1[tid]; s_b2[tid] = b2[tid]; }
    __syncthreads();

    int p = blockIdx.x * 256 + tid;
    if (p >= P_) return;
    float f[10];
    f[0] = (traffic[p]        - 1385.4059f) * (1.f / 859.8119f);
    f[1] = (packets[p]        - 1.4015f)    * (1.f / 0.8933f);
    f[2] = (eq_lambda[p]      - 1350.9712f) * (1.f / 858.3162f);
    f[3] = (avg_pkts_lambda[p]- 0.9117f)    * (1.f / 0.9724f);
    f[4] = (exp_max_factor[p] - 6.6636f)    * (1.f / 4.7151f);
    f[5] = (pkts_lambda_on[p] - 0.9116f)    * (1.f / 1.6513f);
    f[6] = (avg_t_off[p]      - 1.6649f)    * (1.f / 2.3564f);
    f[7] = (avg_t_on[p]       - 1.6649f)    * (1.f / 2.3564f);
    f[8] = ar_a[p];
    f[9] = sigma[p];
    const int mrow = 2 + model[p];
    float h1[32];
#pragma unroll
    for (int d = 0; d < 32; d++) {
        float a = s_b1[d] + s_w1[mrow * 32 + d];
        a += f[0] * s_w1[0 * 32 + d];
        a += f[1] * s_w1[1 * 32 + d];
#pragma unroll
        for (int j = 0; j < 8; j++) a += f[2 + j] * s_w1[(9 + j) * 32 + d];
        h1[d] = fmaxf(a, 0.f);
    }
    float* dst = sps + (size_t)inv[p] * 32;
#pragma unroll
    for (int d = 0; d < 32; d++) {
        float a = s_b2[d];
#pragma unroll
        for (int k = 0; k < 32; k++) a += h1[k] * s_w2[k * 32 + d];
        dst[d] = fmaxf(a, 0.f);
    }
}

// ---------------- queue embed + zq: thread/queue, LDS-staged weights ---------

__global__ __launch_bounds__(256) void k_queue_embed(
    const float* __restrict__ queue_size, const float* __restrict__ weight,
    const int* __restrict__ priority,
    const float* __restrict__ w1, const float* __restrict__ b1,
    const float* __restrict__ w2, const float* __restrict__ b2,
    const float* __restrict__ prW, const float* __restrict__ prB,
    float* __restrict__ queue_state, float* __restrict__ zq)
{
    __shared__ float s_w1[160], s_w2[1024], s_pw[1024], s_b1[32], s_b2[32], s_pb[32];
    const int tid = threadIdx.x;
    if (tid < 160) s_w1[tid] = w1[tid];
    for (int idx = tid; idx < 1024; idx += 256) {
        s_w2[idx] = w2[idx];
        s_pw[idx] = prW[idx];
    }
    if (tid < 32) { s_b1[tid] = b1[tid]; s_b2[tid] = b2[tid]; s_pb[tid] = prB[tid]; }
    __syncthreads();

    int q = blockIdx.x * 256 + tid;
    if (q >= NQ_) return;
    float f0 = (queue_size[q] - 30259.1055f) * (1.f / 21410.0957f);
    float f4 = weight[q];
    int prow = 1 + priority[q];
    float h1[32];
#pragma unroll
    for (int d = 0; d < 32; d++) {
        float a = s_b1[d] + s_w1[prow * 32 + d]
                + f0 * s_w1[0 * 32 + d] + f4 * s_w1[4 * 32 + d];
        h1[d] = fmaxf(a, 0.f);
    }
    float h2[32];
#pragma unroll
    for (int d = 0; d < 32; d++) {
        float a = s_b2[d];
#pragma unroll
        for (int k = 0; k < 32; k++) a += h1[k] * s_w2[k * 32 + d];
        h2[d] = fmaxf(a, 0.f);
        queue_state[q * 32 + d] = h2[d];
    }
#pragma unroll
    for (int d = 0; d < 32; d++) {
        float a = s_pb[d];
#pragma unroll
        for (int k = 0; k < 32; k++) a += h2[k] * s_pw[k * 32 + d];
        zq[q * 32 + d] = a;
    }
}

// ---------------- link embed + zl: wave/link ---------------------------------

__global__ __launch_bounds__(256) void k_link_embed(
    const float* __restrict__ traffic, const float* __restrict__ capacity,
    const int* __restrict__ policy,
    const int* __restrict__ p2l, const int* __restrict__ p2l_deg,
    const float* __restrict__ w1, const float* __restrict__ b1,
    const float* __restrict__ w2, const float* __restrict__ b2,
    const float* __restrict__ prWl,
    float* __restrict__ link_state, float* __restrict__ zl)
{
    __shared__ float wsh[2272];  // w1[160] b1@160 w2@192 b2@1216 prWl@1248
    __shared__ float h1s[4][32];
    __shared__ float h2s[4][32];
    const int tid = threadIdx.x;
    if (tid < 160) wsh[tid] = w1[tid];
    if (tid < 32)  wsh[160 + tid] = b1[tid];
    for (int idx = tid; idx < 1024; idx += 256) {
        wsh[192 + idx]  = w2[idx];
        wsh[1248 + idx] = prWl[idx];
    }
    if (tid >= 32 && tid < 64) wsh[1216 + tid - 32] = b2[tid - 32];
    __syncthreads();

    const int w = tid >> 6, lane = tid & 63;
    const int l = blockIdx.x * 4 + w;          // grid = 500 exact
    const int deg = p2l_deg[l];
    float s = 0.f;
    if (lane < deg)      s += traffic[p2l[l * 256 + 2 * lane]];
    if (lane + 64 < deg) s += traffic[p2l[l * 256 + 2 * (lane + 64)]];
#pragma unroll
    for (int m = 1; m < 64; m <<= 1) s += __shfl_xor(s, m, 64);
    const float load = s / capacity[l];
    const int prow = 1 + policy[l];
    if (lane < 32) {
        float a = wsh[160 + lane] + wsh[prow * 32 + lane] + load * wsh[lane];
        h1s[w][lane] = fmaxf(a, 0.f);
    }
    __syncthreads();
    if (lane < 32) {
        float a = wsh[1216 + lane];
#pragma unroll
        for (int k = 0; k < 32; k++) a += h1s[w][k] * wsh[192 + k * 32 + lane];
        a = fmaxf(a, 0.f);
        link_state[l * 32 + lane] = a;
        h2s[w][lane] = a;
    }
    __syncthreads();
    if (lane < 32) {
        float a = 0.f;
#pragma unroll
        for (int k = 0; k < 32; k++) a += h2s[w][k] * wsh[1248 + k * 32 + lane];
        zl[l * 32 + lane] = a;
    }
}

// ---------------- path RNN: sorted space, len-bounded loop (iters 0..6) ------

__global__ __launch_bounds__(256, 2) void k_path_rnn(
    const int* __restrict__ q2ps, const int* __restrict__ l2ps,
    const int* __restrict__ lens,
    const float* __restrict__ prU,
    const float* __restrict__ zq, const float* __restrict__ zl,
    float* __restrict__ sps, u16* __restrict__ pss)
{
    const int tid = threadIdx.x;
    const int grp = tid >> 3, i = tid & 7;
    const int j = blockIdx.x * 32 + grp;
    if (j >= P_) return;
    const int len = lens[j];

    float4 Ub[32];
#pragma unroll
    for (int s = 0; s < 8; s++) {
        const float* rb = prU + ((i ^ s) * 128 + 4 * i);
#pragma unroll
        for (int c = 0; c < 4; c++)
            Ub[4 * s + c] = *(const float4*)(rb + 32 * c);
    }

    const int4 qi0 = *(const int4*)(q2ps + (size_t)j * 8);
    const int4 qi1 = *(const int4*)(q2ps + (size_t)j * 8 + 4);
    const int4 li0 = *(const int4*)(l2ps + (size_t)j * 8);
    const int4 li1 = *(const int4*)(l2ps + (size_t)j * 8 + 4);
    const int qidx[8] = {qi0.x, qi0.y, qi0.z, qi0.w, qi1.x, qi1.y, qi1.z, qi1.w};
    const int lidx[8] = {li0.x, li0.y, li0.z, li0.w, li1.x, li1.y, li1.z, li1.w};

    float4 own = *(const float4*)(sps + (size_t)j * 32 + 4 * i);
    float hr[32];
    hr_rebuild(hr, own);

    float4 z;
    {
        const float4 a = *(const float4*)(zq + (size_t)qidx[0] * 32 + 4 * i);
        const float4 b = *(const float4*)(zl + (size_t)lidx[0] * 32 + 4 * i);
        z = make_float4(a.x + b.x, a.y + b.y, a.z + b.z, a.w + b.w);
    }

#pragma unroll
    for (int t = 0; t < 8; t++) {
        if (t >= len) break;        // sorted: wave-uniform exit
        float4 acc = z;
        if (t + 1 < len) {          // prefetch next z during the matvec
            const float4 a = *(const float4*)(zq + (size_t)qidx[t + 1] * 32 + 4 * i);
            const float4 b = *(const float4*)(zl + (size_t)lidx[t + 1] * 32 + 4 * i);
            z = make_float4(a.x + b.x, a.y + b.y, a.z + b.z, a.w + b.w);
        }
#pragma unroll
        for (int k = 0; k < 32; k++) {
            const float hk = hr[k];
            acc.x += hk * Ub[k].x; acc.y += hk * Ub[k].y;
            acc.z += hk * Ub[k].z; acc.w += hk * Ub[k].w;
        }
        own = tanh4(acc);
        uint2 w2;
        w2.x = pk2(own.x, own.y);
        w2.y = pk2(own.z, own.w);
        *(uint2*)(pss + (size_t)j * 256 + t * 32 + 4 * i) = w2;
        if (t + 1 < len) hr_rebuild(hr, own);
    }
    *(float4*)(sps + (size_t)j * 32 + 4 * i) = own;
}

// ---------------- last path RNN + fused readout ------------------------------
// Iteration 7's rnn; pss/sps writes are dead (final qupd/lupd are dead in the
// reference, readout is fused here from registers). Per timestep: update h,
// then run the 32->16->16->1 readout MLP fully in-register via butterfly hr.

__global__ __launch_bounds__(256, 2) void k_rnn_last(
    const int* __restrict__ q2ps, const int* __restrict__ l2ps,
    const int* __restrict__ lens, const int* __restrict__ perm,
    const float* __restrict__ prU,
    const float* __restrict__ zq, const float* __restrict__ zl,
    const float* __restrict__ sps,
    const float* __restrict__ capacity,
    const float* __restrict__ traffic, const float* __restrict__ packets,
    const float* __restrict__ w1, const float* __restrict__ b1,
    const float* __restrict__ w2, const float* __restrict__ b2,
    const float* __restrict__ w3, const float* __restrict__ b3,
    const int* __restrict__ flags, void* __restrict__ out)
{
    __shared__ float wl[817];   // w1[512] b1@512 w2@528 b2@784 w3@800 b3@816
    const int tid = threadIdx.x;
    for (int idx = tid; idx < 512; idx += 256) wl[idx] = w1[idx];
    if (tid < 256) wl[528 + tid] = w2[tid];
    if (tid < 16) {
        wl[512 + tid] = b1[tid];
        wl[784 + tid] = b2[tid];
        wl[800 + tid] = w3[tid];
    }
    if (tid == 0) wl[816] = b3[0];
    __syncthreads();

    const int grp = tid >> 3, i = tid & 7;
    const int j = blockIdx.x * 32 + grp;
    if (j >= P_) return;
    const int len = lens[j];

    float4 Ub[32];
#pragma unroll
    for (int s = 0; s < 8; s++) {
        const float* rb = prU + ((i ^ s) * 128 + 4 * i);
#pragma unroll
        for (int c = 0; c < 4; c++)
            Ub[4 * s + c] = *(const float4*)(rb + 32 * c);
    }

    const int4 qi0 = *(const int4*)(q2ps + (size_t)j * 8);
    const int4 qi1 = *(const int4*)(q2ps + (size_t)j * 8 + 4);
    const int4 li0 = *(const int4*)(l2ps + (size_t)j * 8);
    const int4 li1 = *(const int4*)(l2ps + (size_t)j * 8 + 4);
    const int qidx[8] = {qi0.x, qi0.y, qi0.z, qi0.w, qi1.x, qi1.y, qi1.z, qi1.w};
    const int lidx[8] = {li0.x, li0.y, li0.z, li0.w, li1.x, li1.y, li1.z, li1.w};

    float4 own = *(const float4*)(sps + (size_t)j * 32 + 4 * i);
    float hr[32];
    hr_rebuild(hr, own);

    float4 z;
    {
        const float4 a = *(const float4*)(zq + (size_t)qidx[0] * 32 + 4 * i);
        const float4 b = *(const float4*)(zl + (size_t)lidx[0] * 32 + 4 * i);
        z = make_float4(a.x + b.x, a.y + b.y, a.z + b.z, a.w + b.w);
    }

    float qd = 0.f, ts = 0.f;
#pragma unroll
    for (int t = 0; t < 8; t++) {
        if (t >= len) break;
        float4 acc = z;
        if (t + 1 < len) {
            const float4 a = *(const float4*)(zq + (size_t)qidx[t + 1] * 32 + 4 * i);
            const float4 b = *(const float4*)(zl + (size_t)lidx[t + 1] * 32 + 4 * i);
            z = make_float4(a.x + b.x, a.y + b.y, a.z + b.z, a.w + b.w);
        }
#pragma unroll
        for (int k = 0; k < 32; k++) {
            const float hk = hr[k];
            acc.x += hk * Ub[k].x; acc.y += hk * Ub[k].y;
            acc.z += hk * Ub[k].z; acc.w += hk * Ub[k].w;
        }
        own = tanh4(acc);
        hr_rebuild(hr, own);      // needed for both next step and readout

        // readout layer 1: lane computes dims 2i, 2i+1 of 16
        float a0 = wl[512 + 2 * i], a1 = wl[512 + 2 * i + 1];
#pragma unroll
        for (int s = 0; s < 8; s++) {
#pragma unroll
            for (int c = 0; c < 4; c++) {
                const int k = 4 * (i ^ s) + c;
                const float2 u = *(const float2*)&wl[k * 16 + 2 * i];
                const float hk = hr[4 * s + c];
                a0 += hk * u.x; a1 += hk * u.y;
            }
        }
        a0 = fmaxf(a0, 0.f); a1 = fmaxf(a1, 0.f);
        // replicate h2[16] in butterfly order: h2r[2s+c] = h2[2*(i^s)+c]
        float h2r[16];
        h2r[0] = a0; h2r[1] = a1;
#pragma unroll
        for (int c = 0; c < 2; c++) h2r[2 + c] = __shfl_xor(h2r[c], 1, 64);
#pragma unroll
        for (int c = 0; c < 4; c++) h2r[4 + c] = __shfl_xor(h2r[c], 2, 64);
#pragma unroll
        for (int c = 0; c < 8; c++) h2r[8 + c] = __shfl_xor(h2r[c], 4, 64);
        // layer 2: lane computes dims 2i, 2i+1 of 16
        float c0 = wl[784 + 2 * i], c1 = wl[784 + 2 * i + 1];
#pragma unroll
        for (int s = 0; s < 8; s++) {
#pragma unroll
            for (int c = 0; c < 2; c++) {
                const int k = 2 * (i ^ s) + c;
                const float2 u = *(const float2*)&wl[528 + k * 16 + 2 * i];
                const float hk = h2r[2 * s + c];
                c0 += hk * u.x; c1 += hk * u.y;
            }
        }
        c0 = fmaxf(c0, 0.f); c1 = fmaxf(c1, 0.f);
        float pv = c0 * wl[800 + 2 * i] + c1 * wl[800 + 2 * i + 1];
        pv += __shfl_xor(pv, 1, 8);
        pv += __shfl_xor(pv, 2, 8);
        pv += __shfl_xor(pv, 4, 8);
        const float occv = pv + wl[816];
        const float inv = 1.f / capacity[lidx[t]];
        qd += occv * inv;
        ts += inv;
    }
    if (i == 0) {
        const int p = perm[j];
        const float res = qd + (traffic[p] / packets[p]) * ts;
        if (flags[0]) ((float*)out)[p] = res;
        else          ((bf16*)out)[p] = __float2bfloat16(res);
    }
}

// ---------------- queue update: wave/queue, fused zq (iters 0..6) ------------

__global__ __launch_bounds__(256) void k_queue_update(
    const int* __restrict__ p2qs, const int* __restrict__ p2q_deg,
    const float* __restrict__ qrW, const float* __restrict__ qrU,
    const float* __restrict__ qrB,
    const float* __restrict__ prWq, const float* __restrict__ prB,
    const u16* __restrict__ pss, float* __restrict__ queue_state,
    float* __restrict__ zq)
{
    __shared__ float wl[3 * 1024 + 64]; // qrW@0 qrU@1024 prWq@2048 qrB@3072 prB@3104
    const int tid = threadIdx.x;
#pragma unroll
    for (int jj = 0; jj < 4; jj++) {
        wl[tid + 256 * jj]        = qrW[tid + 256 * jj];
        wl[1024 + tid + 256 * jj] = qrU[tid + 256 * jj];
        wl[2048 + tid + 256 * jj] = prWq[tid + 256 * jj];
    }
    if (tid < 32) { wl[3072 + tid] = qrB[tid]; wl[3104 + tid] = prB[tid]; }
    __syncthreads();

    const int w = tid >> 6, lane = tid & 63;
    const int g = lane >> 3, i = lane & 7;
    const int q = blockIdx.x * 4 + w;          // grid = 1500 exact
    const int deg = p2q_deg[q];

    int offs[8];
#pragma unroll
    for (int s = 0; s < 8; s++) offs[s] = (i ^ s) * 128 + 4 * i;

    float4 ps = {0.f, 0.f, 0.f, 0.f};
    for (int j = g; j < deg; j += 8) {
        const int2 pr = ((const int2*)p2qs)[q * 64 + j];
        int pos = pr.y - 1;
        pos = pos < 0 ? 0 : (pos > 7 ? 7 : pos);
        const ushort4 v = *(const ushort4*)(pss + (size_t)pr.x * 256 + pos * 32 + 4 * i);
        ps.x += bfb2f(v.x); ps.y += bfb2f(v.y);
        ps.z += bfb2f(v.z); ps.w += bfb2f(v.w);
    }
#pragma unroll
    for (int m = 8; m < 64; m <<= 1) {
        ps.x += __shfl_xor(ps.x, m, 64);
        ps.y += __shfl_xor(ps.y, m, 64);
        ps.z += __shfl_xor(ps.z, m, 64);
        ps.w += __shfl_xor(ps.w, m, 64);
    }
    const float4 qs = *(const float4*)(queue_state + (size_t)q * 32 + 4 * i);

    float psr[32]; hr_rebuild(psr, ps);
    float qsr[32]; hr_rebuild(qsr, qs);
    float4 acc = *(const float4*)(wl + 3072 + 4 * i);
    acc = matvec32o(psr, wl, offs, acc);
    acc = matvec32o(qsr, wl + 1024, offs, acc);
    const float4 nh = tanh4(acc);

    float nhr[32]; hr_rebuild(nhr, nh);
    float4 zacc = *(const float4*)(wl + 3104 + 4 * i);
    zacc = matvec32o(nhr, wl + 2048, offs, zacc);

    if (g == 0) {
        *(float4*)(queue_state + (size_t)q * 32 + 4 * i) = nh;
        *(float4*)(zq + (size_t)q * 32 + 4 * i) = zacc;
    }
}

// ---------------- link update: wave/link, fused zl (iters 0..6) --------------

__global__ __launch_bounds__(256) void k_link_update(
    const int* __restrict__ q2l,
    const float* __restrict__ lrW, const float* __restrict__ lrU,
    const float* __restrict__ lrB,
    const float* __restrict__ prWl,
    const float* __restrict__ queue_state, float* __restrict__ link_state,
    float* __restrict__ zl)
{
    __shared__ float wl[3 * 1024 + 32]; // lrW@0 lrU@1024 prWl@2048 lrB@3072
    const int tid = threadIdx.x;
#pragma unroll
    for (int jj = 0; jj < 4; jj++) {
        wl[tid + 256 * jj]        = lrW[tid + 256 * jj];
        wl[1024 + tid + 256 * jj] = lrU[tid + 256 * jj];
        wl[2048 + tid + 256 * jj] = prWl[tid + 256 * jj];
    }
    if (tid < 32) wl[3072 + tid] = lrB[tid];
    __syncthreads();

    const int w = tid >> 6, lane = tid & 63;
    const int i = lane & 7, g = lane >> 3;
    const int l = blockIdx.x * 4 + w;          // grid = 500 exact

    int offs[8];
#pragma unroll
    for (int s = 0; s < 8; s++) offs[s] = (i ^ s) * 128 + 4 * i;

    float4 h = *(const float4*)(link_state + (size_t)l * 32 + 4 * i);
    float hhr[32]; hr_rebuild(hhr, h);

#pragma unroll
    for (int t = 0; t < 3; t++) {
        const int qq = q2l[l * 3 + t];
        const float4 qg = *(const float4*)(queue_state + (size_t)qq * 32 + 4 * i);
        float qgr[32]; hr_rebuild(qgr, qg);
        float4 acc = *(const float4*)(wl + 3072 + 4 * i);
        acc = matvec32o(qgr, wl, offs, acc);
        acc = matvec32o(hhr, wl + 1024, offs, acc);
        h = tanh4(acc);
        hr_rebuild(hhr, h);
    }
    float4 zacc = make_float4(0.f, 0.f, 0.f, 0.f);
    zacc = matvec32o(hhr, wl + 2048, offs, zacc);
    if (g == 0) {
        *(float4*)(link_state + (size_t)l * 32 + 4 * i) = h;
        *(float4*)(zl + (size_t)l * 32 + 4 * i) = zacc;
    }
}

// ---------------- launcher ---------------------------------------------------

extern "C" void kernel_launch(void* const* d_in, const int* in_sizes, int n_in,
                              void* d_out, int out_size, void* d_ws, size_t ws_size,
                              hipStream_t stream)
{
    static const int CVT_N[40] = {
        50000,50000,50000,50000,50000,50000,50000,50000,50000,50000,
        2000,6000,6000,
        544,32,1024,32, 160,32,1024,32, 160,32,1024,32,
        2048,1024,32, 1024,1024,32, 1024,1024,32,
        512,16,256,16,16,1};

    const int*  length   = (const int*)d_in[13];
    const int*  model    = (const int*)d_in[14];
    const int*  policy   = (const int*)d_in[15];
    const int*  priority = (const int*)d_in[16];
    const int*  q2p      = (const int*)d_in[17];
    const int*  l2p      = (const int*)d_in[18];
    const int*  p2l      = (const int*)d_in[19];
    const int*  p2l_deg  = (const int*)d_in[20];
    const int*  p2q      = (const int*)d_in[21];
    const int*  p2q_deg  = (const int*)d_in[22];
    const int*  q2l      = (const int*)d_in[23];

    CvtArgs ca;
    for (int i = 0; i < 13; i++) ca.p[i] = d_in[i];
    for (int i = 0; i < 27; i++) ca.p[13 + i] = d_in[24 + i];

    int off[41]; off[0] = 0;
    for (int i = 0; i < 40; i++) off[i + 1] = off[i] + CVT_N[i];
    int nblk = 0;
    for (int i = 0; i < 40; i++) nblk += (CVT_N[i] + 255) / 256;

    float* ws = (float*)d_ws;
    const float* c_traffic    = ws + off[0];
    const float* c_packets    = ws + off[1];
    const float* c_eq_lambda  = ws + off[2];
    const float* c_apl        = ws + off[3];
    const float* c_emf        = ws + off[4];
    const float* c_plo        = ws + off[5];
    const float* c_atoff      = ws + off[6];
    const float* c_aton       = ws + off[7];
    const float* c_ar_a       = ws + off[8];
    const float* c_sigma      = ws + off[9];
    const float* c_capacity   = ws + off[10];
    const float* c_queue_size = ws + off[11];
    const float* c_weight     = ws + off[12];
    const float* c_pe_w1 = ws + off[13]; const float* c_pe_b1 = ws + off[14];
    const float* c_pe_w2 = ws + off[15]; const float* c_pe_b2 = ws + off[16];
    const float* c_le_w1 = ws + off[17]; const float* c_le_b1 = ws + off[18];
    const float* c_le_w2 = ws + off[19]; const float* c_le_b2 = ws + off[20];
    const float* c_qe_w1 = ws + off[21]; const float* c_qe_b1 = ws + off[22];
    const float* c_qe_w2 = ws + off[23]; const float* c_qe_b2 = ws + off[24];
    const float* c_prW = ws + off[25]; const float* c_prU = ws + off[26];
    const float* c_prB = ws + off[27];
    const float* c_qrW = ws + off[28]; const float* c_qrU = ws + off[29];
    const float* c_qrB = ws + off[30];
    const float* c_lrW = ws + off[31]; const float* c_lrU = ws + off[32];
    const float* c_lrB = ws + off[33];
    const float* c_ro_w1 = ws + off[34]; const float* c_ro_b1 = ws + off[35];
    const float* c_ro_w2 = ws + off[36]; const float* c_ro_b2 = ws + off[37];
    const float* c_ro_w3 = ws + off[38]; const float* c_ro_b3 = ws + off[39];

    size_t base = ((size_t)off[40] + 63) & ~(size_t)63;
    float* sps         = ws + base;                          // P*32 (sorted)
    float* queue_state = sps + (size_t)P_ * 32;              // NQ*32
    float* link_state  = queue_state + (size_t)NQ_ * 32;     // NL*32
    float* zq          = link_state + (size_t)NL_ * 32;      // NQ*32
    float* zl          = zq + (size_t)NQ_ * 32;              // NL*32
    u16*   pss         = (u16*)(zl + (size_t)NL_ * 32);      // P*256 bf16 (sorted)
    int*   perm        = (int*)(pss + (size_t)P_ * 256);     // P
    int*   inv         = perm + P_;                          // P
    int*   lens        = inv + P_;                           // P
    int*   q2ps        = lens + P_;                          // P*8
    int*   l2ps        = q2ps + (size_t)P_ * 8;              // P*8
    int*   p2qs        = l2ps + (size_t)P_ * 8;              // NQ*128
    int*   counters    = p2qs + (size_t)NQ_ * 2 * P2Q_;      // hist[8]+cursor[8]+flag
    int*   hist        = counters;
    int*   cursor      = counters + 8;
    int*   flags       = counters + 16;
    // total ws ~43 MB

    k_convert<<<nblk, 256, 0, stream>>>(ca, ws, counters);
    k_hist<<<(P_ + 255) / 256, 256, 0, stream>>>(length, hist);
    k_scatter<<<(P_ + 255) / 256, 256, 0, stream>>>(length, hist, cursor, perm, inv);
    k_remap<<<RA_ + RC_, 256, 0, stream>>>(
        perm, inv, q2p, l2p, length, p2q, q2ps, l2ps, lens, p2qs);

    k_path_embed<<<(P_ + 255) / 256, 256, 0, stream>>>(
        c_traffic, c_packets, c_eq_lambda, c_apl, c_emf, c_plo, c_atoff, c_aton,
        c_ar_a, c_sigma, model, inv, c_pe_w1, c_pe_b1, c_pe_w2, c_pe_b2, sps);
    k_queue_embed<<<(NQ_ + 255) / 256, 256, 0, stream>>>(
        c_queue_size, c_weight, priority, c_qe_w1, c_qe_b1, c_qe_w2, c_qe_b2,
        c_prW, c_prB, queue_state, zq);
    k_link_embed<<<NL_ / 4, 256, 0, stream>>>(
        c_traffic, c_capacity, policy, p2l, p2l_deg,
        c_le_w1, c_le_b1, c_le_w2, c_le_b2, c_prW + 1024, link_state, zl);

    for (int it = 0; it < ITERS_ - 1; ++it) {
        k_path_rnn<<<(P_ + 31) / 32, 256, 0, stream>>>(
            q2ps, l2ps, lens, c_prU, zq, zl, sps, pss);
        k_queue_update<<<NQ_ / 4, 256, 0, stream>>>(
            p2qs, p2q_deg, c_qrW, c_qrU, c_qrB, c_prW, c_prB,
            pss, queue_state, zq);
        k_link_update<<<NL_ / 4, 256, 0, stream>>>(
            q2l, c_lrW, c_lrU, c_lrB, c_prW + 1024,
            queue_state, link_state, zl);
    }

    // iteration 7: rnn with fused readout; final qupd/lupd are dead in the ref
    k_rnn_last<<<(P_ + 31) / 32, 256, 0, stream>>>(
        q2ps, l2ps, lens, perm, c_prU, zq, zl, sps,
        c_capacity, c_traffic, c_packets,
        c_ro_w1, c_ro_b1, c_ro_w2, c_ro_b2, c_ro_w3, c_ro_b3,
        flags, d_out);
}

// Round 12
// 642.460 us; speedup vs baseline: 5.1853x; 1.0425x over previous
//
#include <hip/hip_runtime.h>
#include <hip/hip_bf16.h>

#define P_ 50000
#define NL_ 2000
#define NQ_ 6000
#define L_ 8
#define P2L_ 128
#define P2Q_ 64
#define D_ 32
#define ITERS_ 8
#define RA_ 1563  // remap blocks for path-indexed arrays (P_*8/256)
#define RC_ 1500  // remap blocks for p2q pairs (NQ_*P2Q_/256)

typedef __hip_bfloat16 bf16;
typedef unsigned short u16;
typedef unsigned int u32;

__device__ __forceinline__ float bfb2f(u16 u) {
    union { u32 i; float f; } c; c.i = ((u32)u) << 16; return c.f;
}
__device__ __forceinline__ u16 f2bfb(float f) {
    union { bf16 h; u16 u; } c; c.h = __float2bfloat16(f); return c.u;
}
__device__ __forceinline__ u32 pk2(float a, float b) {
    return (u32)f2bfb(a) | ((u32)f2bfb(b) << 16);
}

__device__ __forceinline__ float tanh_fast(float x) {
    return 1.f - 2.f / (__expf(2.f * x) + 1.f);
}
__device__ __forceinline__ float4 tanh4(float4 a) {
    return make_float4(tanh_fast(a.x), tanh_fast(a.y), tanh_fast(a.z), tanh_fast(a.w));
}

// butterfly-order replicated state: hr[4s+c] = h[4*(i^s)+c] for this lane's i.
__device__ __forceinline__ void hr_rebuild(float* hr, float4 own) {
    hr[0] = own.x; hr[1] = own.y; hr[2] = own.z; hr[3] = own.w;
#pragma unroll
    for (int c = 0; c < 4; c++)  hr[4 + c]  = __shfl_xor(hr[c], 1, 64);
#pragma unroll
    for (int c = 0; c < 8; c++)  hr[8 + c]  = __shfl_xor(hr[c], 2, 64);
#pragma unroll
    for (int c = 0; c < 16; c++) hr[16 + c] = __shfl_xor(hr[c], 4, 64);
}

// acc += full-h @ W[:,4i..4i+3]; W in LDS at base, offs[s] = (i^s)*128+4i
__device__ __forceinline__ float4 matvec32o(const float* hr, const float* base,
                                            const int* offs, float4 acc) {
#pragma unroll
    for (int s = 0; s < 8; s++) {
        const float* u0 = base + offs[s];
#pragma unroll
        for (int c = 0; c < 4; c++) {
            const float4 u = *(const float4*)(u0 + 32 * c);
            const float hk = hr[4 * s + c];
            acc.x += hk * u.x; acc.y += hk * u.y;
            acc.z += hk * u.z; acc.w += hk * u.w;
        }
    }
    return acc;
}

// Runtime dtype probe (see earlier rounds): error prob ~1e-24.
__device__ bool detect_f32(const void* p, int n) {
    const u16* u = (const u16*)p;
    int m = n < 64 ? n : 64;
    bool bad = false;
    for (int k = 0; k < m; k++) {
        float v = bfb2f(u[k]);
        float av = fabsf(v);
        bool sane = (v == v) && (av <= 1e6f) && (av == 0.0f || av >= 1e-8f);
        bad |= !sane;
    }
    return bad;
}

// ---------------- input canonicalization + counter zeroing + dtype flag ------

struct CvtArgs { const void* p[40]; };

__global__ __launch_bounds__(256) void k_convert(CvtArgs a, float* __restrict__ dst,
                                                 int* __restrict__ counters) {
    static constexpr int N[40] = {
        50000,50000,50000,50000,50000,50000,50000,50000,50000,50000,
        2000,6000,6000,
        544,32,1024,32, 160,32,1024,32, 160,32,1024,32,
        2048,1024,32, 1024,1024,32, 1024,1024,32,
        512,16,256,16,16,1};
    if (blockIdx.x == 0 && threadIdx.x < 16) counters[threadIdx.x] = 0;
    int b = blockIdx.x, t = 0, off = 0;
    for (;;) {
        int nb = (N[t] + 255) >> 8;
        if (b < nb) break;
        b -= nb; off += N[t]; ++t;
    }
    const void* src = a.p[t];
    const int n = N[t];
    const bool isf = detect_f32(src, n);
    if (t == 0 && b == 0 && threadIdx.x == 0) counters[16] = isf ? 1 : 0;
    const int i = b * 256 + threadIdx.x;
    if (i < n)
        dst[off + i] = isf ? ((const float*)src)[i] : bfb2f(((const u16*)src)[i]);
}

// ---------------- counting sort by length (DESCENDING: LPT schedule) ---------
// Longest paths get the lowest sorted slots -> their blocks dispatch first,
// short paths pack the tail. Fixes the drain-tail occupancy collapse.

__global__ __launch_bounds__(256) void k_hist(const int* __restrict__ length,
                                              int* __restrict__ hist) {
    __shared__ int hc[8];
    const int tid = threadIdx.x;
    if (tid < 8) hc[tid] = 0;
    __syncthreads();
    int p = blockIdx.x * 256 + tid;
    if (p < P_) atomicAdd(&hc[length[p] - 1], 1);
    __syncthreads();
    if (tid < 8 && hc[tid] > 0) atomicAdd(&hist[tid], hc[tid]);
}

__global__ __launch_bounds__(256) void k_scatter(const int* __restrict__ length,
                                                 const int* __restrict__ hist,
                                                 int* __restrict__ cursor,
                                                 int* __restrict__ perm,
                                                 int* __restrict__ inv) {
    __shared__ int cnt[8];
    __shared__ int base[8];
    const int tid = threadIdx.x;
    if (tid < 8) cnt[tid] = 0;
    __syncthreads();
    const int p = blockIdx.x * 256 + tid;
    int b = 0, r = 0;
    if (p < P_) { b = length[p] - 1; r = atomicAdd(&cnt[b], 1); }
    __syncthreads();
    if (tid < 8) {
        int pre = 0;
#pragma unroll
        for (int k = 0; k < 8; k++) pre += (k > tid) ? hist[k] : 0;  // DESC
        base[tid] = pre + (cnt[tid] > 0 ? atomicAdd(&cursor[tid], cnt[tid]) : 0);
    }
    __syncthreads();
    if (p < P_) { const int pos = base[b] + r; perm[pos] = p; inv[p] = pos; }
}

// ---------------- remap into sorted index space ------------------------------

__global__ __launch_bounds__(256) void k_remap(
    const int* __restrict__ perm, const int* __restrict__ inv,
    const int* __restrict__ q2p, const int* __restrict__ l2p,
    const int* __restrict__ length, const int* __restrict__ p2q,
    int* __restrict__ q2ps, int* __restrict__ l2ps, int* __restrict__ lens,
    int* __restrict__ p2qs)
{
    const int blk = blockIdx.x;
    if (blk < RA_) {
        const int idx = blk * 256 + threadIdx.x;
        if (idx >= P_ * 8) return;
        const int j = idx >> 3, t = idx & 7;
        const int p = perm[j];
        q2ps[idx] = q2p[p * 8 + t];
        l2ps[idx] = l2p[p * 8 + t];
        if (t == 0) lens[j] = length[p];
    } else {
        const int e = (blk - RA_) * 256 + threadIdx.x;
        if (e >= NQ_ * P2Q_) return;
        const int2 pr = ((const int2*)p2q)[e];
        ((int2*)p2qs)[e] = make_int2(inv[pr.x], pr.y);
    }
}

// ---------------- path embed: thread/path, LDS-staged weights ----------------

__global__ __launch_bounds__(256) void k_path_embed(
    const float* __restrict__ traffic, const float* __restrict__ packets,
    const float* __restrict__ eq_lambda, const float* __restrict__ avg_pkts_lambda,
    const float* __restrict__ exp_max_factor, const float* __restrict__ pkts_lambda_on,
    const float* __restrict__ avg_t_off, const float* __restrict__ avg_t_on,
    const float* __restrict__ ar_a, const float* __restrict__ sigma,
    const int* __restrict__ model, const int* __restrict__ inv,
    const float* __restrict__ w1, const float* __restrict__ b1,
    const float* __restrict__ w2, const float* __restrict__ b2,
    float* __restrict__ sps)
{
    __shared__ float s_w1[544], s_w2[1024], s_b1[32], s_b2[32];
    const int tid = threadIdx.x;
    for (int idx = tid; idx < 544; idx += 256)  s_w1[idx] = w1[idx];
    for (int idx = tid; idx < 1024; idx += 256) s_w2[idx] = w2[idx];
    if (tid < 32) { s_b1[tid] = b1[tid]; s_b2[tid] = b2[tid]; }
    __syncthreads();

    int p = blockIdx.x * 256 + tid;
    if (p >= P_) return;
    float f[10];
    f[0] = (traffic[p]        - 1385.4059f) * (1.f / 859.8119f);
    f[1] = (packets[p]        - 1.4015f)    * (1.f / 0.8933f);
    f[2] = (eq_lambda[p]      - 1350.9712f) * (1.f / 858.3162f);
    f[3] = (avg_pkts_lambda[p]- 0.9117f)    * (1.f / 0.9724f);
    f[4] = (exp_max_factor[p] - 6.6636f)    * (1.f / 4.7151f);
    f[5] = (pkts_lambda_on[p] - 0.9116f)    * (1.f / 1.6513f);
    f[6] = (avg_t_off[p]      - 1.6649f)    * (1.f / 2.3564f);
    f[7] = (avg_t_on[p]       - 1.6649f)    * (1.f / 2.3564f);
    f[8] = ar_a[p];
    f[9] = sigma[p];
    const int mrow = 2 + model[p];
    float h1[32];
#pragma unroll
    for (int d = 0; d < 32; d++) {
        float a = s_b1[d] + s_w1[mrow * 32 + d];
        a += f[0] * s_w1[0 * 32 + d];
        a += f[1] * s_w1[1 * 32 + d];
#pragma unroll
        for (int j = 0; j < 8; j++) a += f[2 + j] * s_w1[(9 + j) * 32 + d];
        h1[d] = fmaxf(a, 0.f);
    }
    float* dst = sps + (size_t)inv[p] * 32;
#pragma unroll
    for (int d = 0; d < 32; d++) {
        float a = s_b2[d];
#pragma unroll
        for (int k = 0; k < 32; k++) a += h1[k] * s_w2[k * 32 + d];
        dst[d] = fmaxf(a, 0.f);
    }
}

// ---------------- queue embed + zq: thread/queue, LDS-staged weights ---------

__global__ __launch_bounds__(256) void k_queue_embed(
    const float* __restrict__ queue_size, const float* __restrict__ weight,
    const int* __restrict__ priority,
    const float* __restrict__ w1, const float* __restrict__ b1,
    const float* __restrict__ w2, const float* __restrict__ b2,
    const float* __restrict__ prW, const float* __restrict__ prB,
    float* __restrict__ queue_state, float* __restrict__ zq)
{
    __shared__ float s_w1[160], s_w2[1024], s_pw[1024], s_b1[32], s_b2[32], s_pb[32];
    const int tid = threadIdx.x;
    if (tid < 160) s_w1[tid] = w1[tid];
    for (int idx = tid; idx < 1024; idx += 256) {
        s_w2[idx] = w2[idx];
        s_pw[idx] = prW[idx];
    }
    if (tid < 32) { s_b1[tid] = b1[tid]; s_b2[tid] = b2[tid]; s_pb[tid] = prB[tid]; }
    __syncthreads();

    int q = blockIdx.x * 256 + tid;
    if (q >= NQ_) return;
    float f0 = (queue_size[q] - 30259.1055f) * (1.f / 21410.0957f);
    float f4 = weight[q];
    int prow = 1 + priority[q];
    float h1[32];
#pragma unroll
    for (int d = 0; d < 32; d++) {
        float a = s_b1[d] + s_w1[prow * 32 + d]
                + f0 * s_w1[0 * 32 + d] + f4 * s_w1[4 * 32 + d];
        h1[d] = fmaxf(a, 0.f);
    }
    float h2[32];
#pragma unroll
    for (int d = 0; d < 32; d++) {
        float a = s_b2[d];
#pragma unroll
        for (int k = 0; k < 32; k++) a += h1[k] * s_w2[k * 32 + d];
        h2[d] = fmaxf(a, 0.f);
        queue_state[q * 32 + d] = h2[d];
    }
#pragma unroll
    for (int d = 0; d < 32; d++) {
        float a = s_pb[d];
#pragma unroll
        for (int k = 0; k < 32; k++) a += h2[k] * s_pw[k * 32 + d];
        zq[q * 32 + d] = a;
    }
}

// ---------------- link embed + zl: wave/link ---------------------------------

__global__ __launch_bounds__(256) void k_link_embed(
    const float* __restrict__ traffic, const float* __restrict__ capacity,
    const int* __restrict__ policy,
    const int* __restrict__ p2l, const int* __restrict__ p2l_deg,
    const float* __restrict__ w1, const float* __restrict__ b1,
    const float* __restrict__ w2, const float* __restrict__ b2,
    const float* __restrict__ prWl,
    float* __restrict__ link_state, float* __restrict__ zl)
{
    __shared__ float wsh[2272];  // w1[160] b1@160 w2@192 b2@1216 prWl@1248
    __shared__ float h1s[4][32];
    __shared__ float h2s[4][32];
    const int tid = threadIdx.x;
    if (tid < 160) wsh[tid] = w1[tid];
    if (tid < 32)  wsh[160 + tid] = b1[tid];
    for (int idx = tid; idx < 1024; idx += 256) {
        wsh[192 + idx]  = w2[idx];
        wsh[1248 + idx] = prWl[idx];
    }
    if (tid >= 32 && tid < 64) wsh[1216 + tid - 32] = b2[tid - 32];
    __syncthreads();

    const int w = tid >> 6, lane = tid & 63;
    const int l = blockIdx.x * 4 + w;          // grid = 500 exact
    const int deg = p2l_deg[l];
    float s = 0.f;
    if (lane < deg)      s += traffic[p2l[l * 256 + 2 * lane]];
    if (lane + 64 < deg) s += traffic[p2l[l * 256 + 2 * (lane + 64)]];
#pragma unroll
    for (int m = 1; m < 64; m <<= 1) s += __shfl_xor(s, m, 64);
    const float load = s / capacity[l];
    const int prow = 1 + policy[l];
    if (lane < 32) {
        float a = wsh[160 + lane] + wsh[prow * 32 + lane] + load * wsh[lane];
        h1s[w][lane] = fmaxf(a, 0.f);
    }
    __syncthreads();
    if (lane < 32) {
        float a = wsh[1216 + lane];
#pragma unroll
        for (int k = 0; k < 32; k++) a += h1s[w][k] * wsh[192 + k * 32 + lane];
        a = fmaxf(a, 0.f);
        link_state[l * 32 + lane] = a;
        h2s[w][lane] = a;
    }
    __syncthreads();
    if (lane < 32) {
        float a = 0.f;
#pragma unroll
        for (int k = 0; k < 32; k++) a += h2s[w][k] * wsh[1248 + k * 32 + lane];
        zl[l * 32 + lane] = a;
    }
}

// ---------------- path RNN: sorted space, len-bounded loop (iters 0..6) ------

__global__ __launch_bounds__(256, 2) void k_path_rnn(
    const int* __restrict__ q2ps, const int* __restrict__ l2ps,
    const int* __restrict__ lens,
    const float* __restrict__ prU,
    const float* __restrict__ zq, const float* __restrict__ zl,
    float* __restrict__ sps, u16* __restrict__ pss)
{
    const int tid = threadIdx.x;
    const int grp = tid >> 3, i = tid & 7;
    const int j = blockIdx.x * 32 + grp;
    if (j >= P_) return;
    const int len = lens[j];

    float4 Ub[32];
#pragma unroll
    for (int s = 0; s < 8; s++) {
        const float* rb = prU + ((i ^ s) * 128 + 4 * i);
#pragma unroll
        for (int c = 0; c < 4; c++)
            Ub[4 * s + c] = *(const float4*)(rb + 32 * c);
    }

    const int4 qi0 = *(const int4*)(q2ps + (size_t)j * 8);
    const int4 qi1 = *(const int4*)(q2ps + (size_t)j * 8 + 4);
    const int4 li0 = *(const int4*)(l2ps + (size_t)j * 8);
    const int4 li1 = *(const int4*)(l2ps + (size_t)j * 8 + 4);
    const int qidx[8] = {qi0.x, qi0.y, qi0.z, qi0.w, qi1.x, qi1.y, qi1.z, qi1.w};
    const int lidx[8] = {li0.x, li0.y, li0.z, li0.w, li1.x, li1.y, li1.z, li1.w};

    float4 own = *(const float4*)(sps + (size_t)j * 32 + 4 * i);
    float hr[32];
    hr_rebuild(hr, own);

    float4 z;
    {
        const float4 a = *(const float4*)(zq + (size_t)qidx[0] * 32 + 4 * i);
        const float4 b = *(const float4*)(zl + (size_t)lidx[0] * 32 + 4 * i);
        z = make_float4(a.x + b.x, a.y + b.y, a.z + b.z, a.w + b.w);
    }

#pragma unroll
    for (int t = 0; t < 8; t++) {
        if (t >= len) break;        // sorted: wave-uniform exit
        float4 acc = z;
        if (t + 1 < len) {          // prefetch next z during the matvec
            const float4 a = *(const float4*)(zq + (size_t)qidx[t + 1] * 32 + 4 * i);
            const float4 b = *(const float4*)(zl + (size_t)lidx[t + 1] * 32 + 4 * i);
            z = make_float4(a.x + b.x, a.y + b.y, a.z + b.z, a.w + b.w);
        }
#pragma unroll
        for (int k = 0; k < 32; k++) {
            const float hk = hr[k];
            acc.x += hk * Ub[k].x; acc.y += hk * Ub[k].y;
            acc.z += hk * Ub[k].z; acc.w += hk * Ub[k].w;
        }
        own = tanh4(acc);
        uint2 w2;
        w2.x = pk2(own.x, own.y);
        w2.y = pk2(own.z, own.w);
        *(uint2*)(pss + (size_t)j * 256 + t * 32 + 4 * i) = w2;
        if (t + 1 < len) hr_rebuild(hr, own);
    }
    *(float4*)(sps + (size_t)j * 32 + 4 * i) = own;
}

// ---------------- last path RNN + fused readout ------------------------------

__global__ __launch_bounds__(256, 2) void k_rnn_last(
    const int* __restrict__ q2ps, const int* __restrict__ l2ps,
    const int* __restrict__ lens, const int* __restrict__ perm,
    const float* __restrict__ prU,
    const float* __restrict__ zq, const float* __restrict__ zl,
    const float* __restrict__ sps,
    const float* __restrict__ capacity,
    const float* __restrict__ traffic, const float* __restrict__ packets,
    const float* __restrict__ w1, const float* __restrict__ b1,
    const float* __restrict__ w2, const float* __restrict__ b2,
    const float* __restrict__ w3, const float* __restrict__ b3,
    const int* __restrict__ flags, void* __restrict__ out)
{
    __shared__ float wl[817];   // w1[512] b1@512 w2@528 b2@784 w3@800 b3@816
    const int tid = threadIdx.x;
    for (int idx = tid; idx < 512; idx += 256) wl[idx] = w1[idx];
    if (tid < 256) wl[528 + tid] = w2[tid];
    if (tid < 16) {
        wl[512 + tid] = b1[tid];
        wl[784 + tid] = b2[tid];
        wl[800 + tid] = w3[tid];
    }
    if (tid == 0) wl[816] = b3[0];
    __syncthreads();

    const int grp = tid >> 3, i = tid & 7;
    const int j = blockIdx.x * 32 + grp;
    if (j >= P_) return;
    const int len = lens[j];

    float4 Ub[32];
#pragma unroll
    for (int s = 0; s < 8; s++) {
        const float* rb = prU + ((i ^ s) * 128 + 4 * i);
#pragma unroll
        for (int c = 0; c < 4; c++)
            Ub[4 * s + c] = *(const float4*)(rb + 32 * c);
    }

    const int4 qi0 = *(const int4*)(q2ps + (size_t)j * 8);
    const int4 qi1 = *(const int4*)(q2ps + (size_t)j * 8 + 4);
    const int4 li0 = *(const int4*)(l2ps + (size_t)j * 8);
    const int4 li1 = *(const int4*)(l2ps + (size_t)j * 8 + 4);
    const int qidx[8] = {qi0.x, qi0.y, qi0.z, qi0.w, qi1.x, qi1.y, qi1.z, qi1.w};
    const int lidx[8] = {li0.x, li0.y, li0.z, li0.w, li1.x, li1.y, li1.z, li1.w};

    float4 own = *(const float4*)(sps + (size_t)j * 32 + 4 * i);
    float hr[32];
    hr_rebuild(hr, own);

    float4 z;
    {
        const float4 a = *(const float4*)(zq + (size_t)qidx[0] * 32 + 4 * i);
        const float4 b = *(const float4*)(zl + (size_t)lidx[0] * 32 + 4 * i);
        z = make_float4(a.x + b.x, a.y + b.y, a.z + b.z, a.w + b.w);
    }

    float qd = 0.f, ts = 0.f;
#pragma unroll
    for (int t = 0; t < 8; t++) {
        if (t >= len) break;
        float4 acc = z;
        if (t + 1 < len) {
            const float4 a = *(const float4*)(zq + (size_t)qidx[t + 1] * 32 + 4 * i);
            const float4 b = *(const float4*)(zl + (size_t)lidx[t + 1] * 32 + 4 * i);
            z = make_float4(a.x + b.x, a.y + b.y, a.z + b.z, a.w + b.w);
        }
#pragma unroll
        for (int k = 0; k < 32; k++) {
            const float hk = hr[k];
            acc.x += hk * Ub[k].x; acc.y += hk * Ub[k].y;
            acc.z += hk * Ub[k].z; acc.w += hk * Ub[k].w;
        }
        own = tanh4(acc);
        hr_rebuild(hr, own);      // needed for both next step and readout

        // readout layer 1: lane computes dims 2i, 2i+1 of 16
        float a0 = wl[512 + 2 * i], a1 = wl[512 + 2 * i + 1];
#pragma unroll
        for (int s = 0; s < 8; s++) {
#pragma unroll
            for (int c = 0; c < 4; c++) {
                const int k = 4 * (i ^ s) + c;
                const float2 u = *(const float2*)&wl[k * 16 + 2 * i];
                const float hk = hr[4 * s + c];
                a0 += hk * u.x; a1 += hk * u.y;
            }
        }
        a0 = fmaxf(a0, 0.f); a1 = fmaxf(a1, 0.f);
        // replicate h2[16] in butterfly order: h2r[2s+c] = h2[2*(i^s)+c]
        float h2r[16];
        h2r[0] = a0; h2r[1] = a1;
#pragma unroll
        for (int c = 0; c < 2; c++) h2r[2 + c] = __shfl_xor(h2r[c], 1, 64);
#pragma unroll
        for (int c = 0; c < 4; c++) h2r[4 + c] = __shfl_xor(h2r[c], 2, 64);
#pragma unroll
        for (int c = 0; c < 8; c++) h2r[8 + c] = __shfl_xor(h2r[c], 4, 64);
        // layer 2: lane computes dims 2i, 2i+1 of 16
        float c0 = wl[784 + 2 * i], c1 = wl[784 + 2 * i + 1];
#pragma unroll
        for (int s = 0; s < 8; s++) {
#pragma unroll
            for (int c = 0; c < 2; c++) {
                const int k = 2 * (i ^ s) + c;
                const float2 u = *(const float2*)&wl[528 + k * 16 + 2 * i];
                const float hk = h2r[2 * s + c];
                c0 += hk * u.x; c1 += hk * u.y;
            }
        }
        c0 = fmaxf(c0, 0.f); c1 = fmaxf(c1, 0.f);
        float pv = c0 * wl[800 + 2 * i] + c1 * wl[800 + 2 * i + 1];
        pv += __shfl_xor(pv, 1, 8);
        pv += __shfl_xor(pv, 2, 8);
        pv += __shfl_xor(pv, 4, 8);
        const float occv = pv + wl[816];
        const float inv = 1.f / capacity[lidx[t]];
        qd += occv * inv;
        ts += inv;
    }
    if (i == 0) {
        const int p = perm[j];
        const float res = qd + (traffic[p] / packets[p]) * ts;
        if (flags[0]) ((float*)out)[p] = res;
        else          ((bf16*)out)[p] = __float2bfloat16(res);
    }
}

// ---------------- queue update: wave/queue, fused zq (iters 0..6) ------------

__global__ __launch_bounds__(256) void k_queue_update(
    const int* __restrict__ p2qs, const int* __restrict__ p2q_deg,
    const float* __restrict__ qrW, const float* __restrict__ qrU,
    const float* __restrict__ qrB,
    const float* __restrict__ prWq, const float* __restrict__ prB,
    const u16* __restrict__ pss, float* __restrict__ queue_state,
    float* __restrict__ zq)
{
    __shared__ float wl[3 * 1024 + 64]; // qrW@0 qrU@1024 prWq@2048 qrB@3072 prB@3104
    const int tid = threadIdx.x;
#pragma unroll
    for (int jj = 0; jj < 4; jj++) {
        wl[tid + 256 * jj]        = qrW[tid + 256 * jj];
        wl[1024 + tid + 256 * jj] = qrU[tid + 256 * jj];
        wl[2048 + tid + 256 * jj] = prWq[tid + 256 * jj];
    }
    if (tid < 32) { wl[3072 + tid] = qrB[tid]; wl[3104 + tid] = prB[tid]; }
    __syncthreads();

    const int w = tid >> 6, lane = tid & 63;
    const int g = lane >> 3, i = lane & 7;
    const int q = blockIdx.x * 4 + w;          // grid = 1500 exact
    const int deg = p2q_deg[q];

    int offs[8];
#pragma unroll
    for (int s = 0; s < 8; s++) offs[s] = (i ^ s) * 128 + 4 * i;

    float4 ps = {0.f, 0.f, 0.f, 0.f};
    for (int j = g; j < deg; j += 8) {
        const int2 pr = ((const int2*)p2qs)[q * 64 + j];
        int pos = pr.y - 1;
        pos = pos < 0 ? 0 : (pos > 7 ? 7 : pos);
        const ushort4 v = *(const ushort4*)(pss + (size_t)pr.x * 256 + pos * 32 + 4 * i);
        ps.x += bfb2f(v.x); ps.y += bfb2f(v.y);
        ps.z += bfb2f(v.z); ps.w += bfb2f(v.w);
    }
#pragma unroll
    for (int m = 8; m < 64; m <<= 1) {
        ps.x += __shfl_xor(ps.x, m, 64);
        ps.y += __shfl_xor(ps.y, m, 64);
        ps.z += __shfl_xor(ps.z, m, 64);
        ps.w += __shfl_xor(ps.w, m, 64);
    }
    const float4 qs = *(const float4*)(queue_state + (size_t)q * 32 + 4 * i);

    float psr[32]; hr_rebuild(psr, ps);
    float qsr[32]; hr_rebuild(qsr, qs);
    float4 acc = *(const float4*)(wl + 3072 + 4 * i);
    acc = matvec32o(psr, wl, offs, acc);
    acc = matvec32o(qsr, wl + 1024, offs, acc);
    const float4 nh = tanh4(acc);

    float nhr[32]; hr_rebuild(nhr, nh);
    float4 zacc = *(const float4*)(wl + 3104 + 4 * i);
    zacc = matvec32o(nhr, wl + 2048, offs, zacc);

    if (g == 0) {
        *(float4*)(queue_state + (size_t)q * 32 + 4 * i) = nh;
        *(float4*)(zq + (size_t)q * 32 + 4 * i) = zacc;
    }
}

// ---------------- link update: wave/link, fused zl (iters 0..6) --------------

__global__ __launch_bounds__(256) void k_link_update(
    const int* __restrict__ q2l,
    const float* __restrict__ lrW, const float* __restrict__ lrU,
    const float* __restrict__ lrB,
    const float* __restrict__ prWl,
    const float* __restrict__ queue_state, float* __restrict__ link_state,
    float* __restrict__ zl)
{
    __shared__ float wl[3 * 1024 + 32]; // lrW@0 lrU@1024 prWl@2048 lrB@3072
    const int tid = threadIdx.x;
#pragma unroll
    for (int jj = 0; jj < 4; jj++) {
        wl[tid + 256 * jj]        = lrW[tid + 256 * jj];
        wl[1024 + tid + 256 * jj] = lrU[tid + 256 * jj];
        wl[2048 + tid + 256 * jj] = prWl[tid + 256 * jj];
    }
    if (tid < 32) wl[3072 + tid] = lrB[tid];
    __syncthreads();

    const int w = tid >> 6, lane = tid & 63;
    const int i = lane & 7, g = lane >> 3;
    const int l = blockIdx.x * 4 + w;          // grid = 500 exact

    int offs[8];
#pragma unroll
    for (int s = 0; s < 8; s++) offs[s] = (i ^ s) * 128 + 4 * i;

    float4 h = *(const float4*)(link_state + (size_t)l * 32 + 4 * i);
    float hhr[32]; hr_rebuild(hhr, h);

#pragma unroll
    for (int t = 0; t < 3; t++) {
        const int qq = q2l[l * 3 + t];
        const float4 qg = *(const float4*)(queue_state + (size_t)qq * 32 + 4 * i);
        float qgr[32]; hr_rebuild(qgr, qg);
        float4 acc = *(const float4*)(wl + 3072 + 4 * i);
        acc = matvec32o(qgr, wl, offs, acc);
        acc = matvec32o(hhr, wl + 1024, offs, acc);
        h = tanh4(acc);
        hr_rebuild(hhr, h);
    }
    float4 zacc = make_float4(0.f, 0.f, 0.f, 0.f);
    zacc = matvec32o(hhr, wl + 2048, offs, zacc);
    if (g == 0) {
        *(float4*)(link_state + (size_t)l * 32 + 4 * i) = h;
        *(float4*)(zl + (size_t)l * 32 + 4 * i) = zacc;
    }
}

// ---------------- launcher ---------------------------------------------------

extern "C" void kernel_launch(void* const* d_in, const int* in_sizes, int n_in,
                              void* d_out, int out_size, void* d_ws, size_t ws_size,
                              hipStream_t stream)
{
    static const int CVT_N[40] = {
        50000,50000,50000,50000,50000,50000,50000,50000,50000,50000,
        2000,6000,6000,
        544,32,1024,32, 160,32,1024,32, 160,32,1024,32,
        2048,1024,32, 1024,1024,32, 1024,1024,32,
        512,16,256,16,16,1};

    const int*  length   = (const int*)d_in[13];
    const int*  model    = (const int*)d_in[14];
    const int*  policy   = (const int*)d_in[15];
    const int*  priority = (const int*)d_in[16];
    const int*  q2p      = (const int*)d_in[17];
    const int*  l2p      = (const int*)d_in[18];
    const int*  p2l      = (const int*)d_in[19];
    const int*  p2l_deg  = (const int*)d_in[20];
    const int*  p2q      = (const int*)d_in[21];
    const int*  p2q_deg  = (const int*)d_in[22];
    const int*  q2l      = (const int*)d_in[23];

    CvtArgs ca;
    for (int i = 0; i < 13; i++) ca.p[i] = d_in[i];
    for (int i = 0; i < 27; i++) ca.p[13 + i] = d_in[24 + i];

    int off[41]; off[0] = 0;
    for (int i = 0; i < 40; i++) off[i + 1] = off[i] + CVT_N[i];
    int nblk = 0;
    for (int i = 0; i < 40; i++) nblk += (CVT_N[i] + 255) / 256;

    float* ws = (float*)d_ws;
    const float* c_traffic    = ws + off[0];
    const float* c_packets    = ws + off[1];
    const float* c_eq_lambda  = ws + off[2];
    const float* c_apl        = ws + off[3];
    const float* c_emf        = ws + off[4];
    const float* c_plo        = ws + off[5];
    const float* c_atoff      = ws + off[6];
    const float* c_aton       = ws + off[7];
    const float* c_ar_a       = ws + off[8];
    const float* c_sigma      = ws + off[9];
    const float* c_capacity   = ws + off[10];
    const float* c_queue_size = ws + off[11];
    const float* c_weight     = ws + off[12];
    const float* c_pe_w1 = ws + off[13]; const float* c_pe_b1 = ws + off[14];
    const float* c_pe_w2 = ws + off[15]; const float* c_pe_b2 = ws + off[16];
    const float* c_le_w1 = ws + off[17]; const float* c_le_b1 = ws + off[18];
    const float* c_le_w2 = ws + off[19]; const float* c_le_b2 = ws + off[20];
    const float* c_qe_w1 = ws + off[21]; const float* c_qe_b1 = ws + off[22];
    const float* c_qe_w2 = ws + off[23]; const float* c_qe_b2 = ws + off[24];
    const float* c_prW = ws + off[25]; const float* c_prU = ws + off[26];
    const float* c_prB = ws + off[27];
    const float* c_qrW = ws + off[28]; const float* c_qrU = ws + off[29];
    const float* c_qrB = ws + off[30];
    const float* c_lrW = ws + off[31]; const float* c_lrU = ws + off[32];
    const float* c_lrB = ws + off[33];
    const float* c_ro_w1 = ws + off[34]; const float* c_ro_b1 = ws + off[35];
    const float* c_ro_w2 = ws + off[36]; const float* c_ro_b2 = ws + off[37];
    const float* c_ro_w3 = ws + off[38]; const float* c_ro_b3 = ws + off[39];

    size_t base = ((size_t)off[40] + 63) & ~(size_t)63;
    float* sps         = ws + base;                          // P*32 (sorted)
    float* queue_state = sps + (size_t)P_ * 32;              // NQ*32
    float* link_state  = queue_state + (size_t)NQ_ * 32;     // NL*32
    float* zq          = link_state + (size_t)NL_ * 32;      // NQ*32
    float* zl          = zq + (size_t)NQ_ * 32;              // NL*32
    u16*   pss         = (u16*)(zl + (size_t)NL_ * 32);      // P*256 bf16 (sorted)
    int*   perm        = (int*)(pss + (size_t)P_ * 256);     // P
    int*   inv         = perm + P_;                          // P
    int*   lens        = inv + P_;                           // P
    int*   q2ps        = lens + P_;                          // P*8
    int*   l2ps        = q2ps + (size_t)P_ * 8;              // P*8
    int*   p2qs        = l2ps + (size_t)P_ * 8;              // NQ*128
    int*   counters    = p2qs + (size_t)NQ_ * 2 * P2Q_;      // hist[8]+cursor[8]+flag
    int*   hist        = counters;
    int*   cursor      = counters + 8;
    int*   flags       = counters + 16;
    // total ws ~43 MB

    k_convert<<<nblk, 256, 0, stream>>>(ca, ws, counters);
    k_hist<<<(P_ + 255) / 256, 256, 0, stream>>>(length, hist);
    k_scatter<<<(P_ + 255) / 256, 256, 0, stream>>>(length, hist, cursor, perm, inv);
    k_remap<<<RA_ + RC_, 256, 0, stream>>>(
        perm, inv, q2p, l2p, length, p2q, q2ps, l2ps, lens, p2qs);

    k_path_embed<<<(P_ + 255) / 256, 256, 0, stream>>>(
        c_traffic, c_packets, c_eq_lambda, c_apl, c_emf, c_plo, c_atoff, c_aton,
        c_ar_a, c_sigma, model, inv, c_pe_w1, c_pe_b1, c_pe_w2, c_pe_b2, sps);
    k_queue_embed<<<(NQ_ + 255) / 256, 256, 0, stream>>>(
        c_queue_size, c_weight, priority, c_qe_w1, c_qe_b1, c_qe_w2, c_qe_b2,
        c_prW, c_prB, queue_state, zq);
    k_link_embed<<<NL_ / 4, 256, 0, stream>>>(
        c_traffic, c_capacity, policy, p2l, p2l_deg,
        c_le_w1, c_le_b1, c_le_w2, c_le_b2, c_prW + 1024, link_state, zl);

    for (int it = 0; it < ITERS_ - 1; ++it) {
        k_path_rnn<<<(P_ + 31) / 32, 256, 0, stream>>>(
            q2ps, l2ps, lens, c_prU, zq, zl, sps, pss);
        k_queue_update<<<NQ_ / 4, 256, 0, stream>>>(
            p2qs, p2q_deg, c_qrW, c_qrU, c_qrB, c_prW, c_prB,
            pss, queue_state, zq);
        k_link_update<<<NL_ / 4, 256, 0, stream>>>(
            q2l, c_lrW, c_lrU, c_lrB, c_prW + 1024,
            queue_state, link_state, zl);
    }

    // iteration 7: rnn with fused readout; final qupd/lupd are dead in the ref
    k_rnn_last<<<(P_ + 31) / 32, 256, 0, stream>>>(
        q2ps, l2ps, lens, perm, c_prU, zq, zl, sps,
        c_capacity, c_traffic, c_packets,
        c_ro_w1, c_ro_b1, c_ro_w2, c_ro_b2, c_ro_w3, c_ro_b3,
        flags, d_out);
}